// Round 8
// baseline (291.549 us; speedup 1.0000x reference)
//
#include <hip/hip_runtime.h>
#include <hip/hip_bf16.h>
#include <math.h>

using bf16 = __hip_bfloat16;
typedef __attribute__((ext_vector_type(8))) short bf16x8;
typedef __attribute__((ext_vector_type(4))) float f32x4;

#define BB   4
#define TT   2048
#define DD   1024
#define HH   16
#define HD_  64
#define LAT_ 128
#define RP   32
#define EPS_ 1e-6f

static __device__ __forceinline__ void stf(float* p, float v) { *p = v; }
static __device__ __forceinline__ void stf(bf16* p, float v) { *p = __float2bfloat16(v); }

// global -> LDS 16B DMA (wave-uniform LDS base + lane*16)
static __device__ __forceinline__ void gl2lds16(const void* g, void* l)
{
    __builtin_amdgcn_global_load_lds(
        (const __attribute__((address_space(1))) void*)g,
        (__attribute__((address_space(3))) void*)l, 16, 0, 0);
}

__global__ __launch_bounds__(256)
void sentinel_kernel(float* __restrict__ out, float val, long long n)
{
    long long i = (long long)blockIdx.x * 256 + threadIdx.x;
    if (i < n) out[i] = val;
}

// ---------------------------------------------------------------------------
// Converters
// ---------------------------------------------------------------------------
// x fp32 -> bf16, 4 elems/thread (float4 in, 8B out)
__global__ __launch_bounds__(256)
void conv_x_kernel(const float* __restrict__ x, bf16* __restrict__ xb, long long n4)
{
    long long i = (long long)blockIdx.x * 256 + threadIdx.x;
    if (i >= n4) return;
    float4 v = *(const float4*)(x + i * 4);
    union { bf16 h[4]; uint2 u; } o;
    o.h[0] = __float2bfloat16(v.x);
    o.h[1] = __float2bfloat16(v.y);
    o.h[2] = __float2bfloat16(v.z);
    o.h[3] = __float2bfloat16(v.w);
    *(uint2*)(xb + i * 4) = o.u;
}

// Tiled transpose-convert: W (K x N fp32 row-major) -> WT (N x K bf16).
__global__ __launch_bounds__(256)
void conv_trans_kernel(const float* __restrict__ W, bf16* __restrict__ WT,
                       int K, int N)
{
    __shared__ __align__(16) bf16 t[64][72];
    const int k0 = blockIdx.y * 64, n0 = blockIdx.x * 64;
    const int tid = threadIdx.x;
    const int r = tid >> 2, c0 = (tid & 3) * 16;
    const float* src = W + (size_t)(k0 + r) * N + n0 + c0;
    #pragma unroll
    for (int j = 0; j < 16; j += 4) {
        float4 v = *(const float4*)(src + j);
        t[c0 + j + 0][r] = __float2bfloat16(v.x);
        t[c0 + j + 1][r] = __float2bfloat16(v.y);
        t[c0 + j + 2][r] = __float2bfloat16(v.z);
        t[c0 + j + 3][r] = __float2bfloat16(v.w);
    }
    __syncthreads();
    const int rr = tid >> 2, cc = (tid & 3) * 16;
    bf16* dst = WT + (size_t)(n0 + rr) * K + k0 + cc;
    *(bf16x8*)dst       = *(const bf16x8*)&t[rr][cc];
    *(bf16x8*)(dst + 8) = *(const bf16x8*)&t[rr][cc + 8];
}

// [Wk | Wv] (each 128x512) -> WT (1024 x 128).
__global__ __launch_bounds__(256)
void conv_wkwv_kernel(const float* __restrict__ Wk, const float* __restrict__ Wv,
                      bf16* __restrict__ WT)
{
    int idx = blockIdx.x * 256 + threadIdx.x;      // 128*1024
    if (idx >= 128 * 1024) return;
    int k = idx >> 10, n = idx & 1023;
    float v = (n < 512) ? Wk[k * 512 + n] : Wv[k * 512 + (n - 512)];
    WT[(size_t)n * 128 + k] = __float2bfloat16(v);
}

// Wo (1024x1024) -> woT (1024 x 512) tiled transpose with row remap.
__global__ __launch_bounds__(256)
void conv_woT_kernel(const float* __restrict__ Wo, bf16* __restrict__ WT)
{
    __shared__ __align__(16) bf16 t[64][72];
    const int mm0 = blockIdx.y * 64, n0 = blockIdx.x * 64;
    const int tid = threadIdx.x;
    const int r = tid >> 2, c0 = (tid & 3) * 16;
    const int mm = mm0 + r;
    const int row = ((mm >> 5) << 6) | (mm & 31);
    const float* src = Wo + (size_t)row * 1024 + n0 + c0;
    #pragma unroll
    for (int j = 0; j < 16; j += 4) {
        float4 v = *(const float4*)(src + j);
        t[c0 + j + 0][r] = __float2bfloat16(v.x);
        t[c0 + j + 1][r] = __float2bfloat16(v.y);
        t[c0 + j + 2][r] = __float2bfloat16(v.z);
        t[c0 + j + 3][r] = __float2bfloat16(v.w);
    }
    __syncthreads();
    const int rr = tid >> 2, cc = (tid & 3) * 16;
    bf16* dst = WT + (size_t)(n0 + rr) * 512 + mm0 + cc;
    *(bf16x8*)dst       = *(const bf16x8*)&t[rr][cc];
    *(bf16x8*)(dst + 8) = *(const bf16x8*)&t[rr][cc + 8];
}

// ---------------------------------------------------------------------------
// MFMA GEMM with global_load_lds staging. C[M,N] = A @ B, A bf16 (M x K)
// row-major, BT bf16 (N x K) row-major. 128x128 tile, BK=32.
// Fragment maps (HW-verified): A[m=lane&15][k=quad*8+j],
// BT[n=lane&15][k=quad*8+j], C/D row=quad*4+reg, col=lane&15.
// ---------------------------------------------------------------------------
#define GEMM_PROLOG_128 \
    __shared__ __align__(16) short As[128][32]; \
    __shared__ __align__(16) short Bs[128][32]; \
    const int tid  = threadIdx.x; \
    const int wave = tid >> 6, lane = tid & 63; \
    const int quad = lane >> 4, l16 = lane & 15; \
    const int wr = (wave >> 1) * 64, wc = (wave & 1) * 64; \
    const int row0 = blockIdx.y * 128, col0 = blockIdx.x * 128; \
    const int srow = tid >> 2, scol = (tid & 3) * 8; \
    char* lAs0 = (char*)As + wave * 1024; \
    char* lAs1 = (char*)As + 4096 + wave * 1024; \
    char* lBs0 = (char*)Bs + wave * 1024; \
    char* lBs1 = (char*)Bs + 4096 + wave * 1024; \
    f32x4 acc[4][4]; \
    _Pragma("unroll") \
    for (int mt = 0; mt < 4; ++mt) \
        _Pragma("unroll") \
        for (int nt = 0; nt < 4; ++nt) \
            acc[mt][nt] = (f32x4){0.f, 0.f, 0.f, 0.f}; \
    for (int k0 = 0; k0 < K; k0 += 32) { \
        const short* ga = A  + (size_t)(row0 + srow) * K + k0 + scol; \
        const short* gb = BT + (size_t)(col0 + srow) * K + k0 + scol; \
        __syncthreads(); \
        gl2lds16(ga,                  lAs0); \
        gl2lds16(ga + (size_t)64 * K, lAs1); \
        gl2lds16(gb,                  lBs0); \
        gl2lds16(gb + (size_t)64 * K, lBs1); \
        __syncthreads(); \
        bf16x8 af[4], bfv[4]; \
        _Pragma("unroll") \
        for (int mt = 0; mt < 4; ++mt) \
            af[mt] = *(const bf16x8*)&As[wr + mt * 16 + l16][quad * 8]; \
        _Pragma("unroll") \
        for (int nt = 0; nt < 4; ++nt) \
            bfv[nt] = *(const bf16x8*)&Bs[wc + nt * 16 + l16][quad * 8]; \
        _Pragma("unroll") \
        for (int mt = 0; mt < 4; ++mt) \
            _Pragma("unroll") \
            for (int nt = 0; nt < 4; ++nt) \
                acc[mt][nt] = __builtin_amdgcn_mfma_f32_16x16x32_bf16( \
                    af[mt], bfv[nt], acc[mt][nt], 0, 0, 0); \
    }

template <typename OT>
__global__ __launch_bounds__(256)
void gemm_mfma(const short* __restrict__ A, const short* __restrict__ BT,
               OT* __restrict__ C, int M, int N, int K)
{
    GEMM_PROLOG_128
    #pragma unroll
    for (int mt = 0; mt < 4; ++mt)
        #pragma unroll
        for (int nt = 0; nt < 4; ++nt) {
            const int col = col0 + wc + nt * 16 + l16;
            #pragma unroll
            for (int r = 0; r < 4; ++r) {
                const int row = row0 + wr + mt * 16 + quad * 4 + r;
                stf(C + (size_t)row * N + col, acc[mt][nt][r]);
            }
        }
}

// ---------------------------------------------------------------------------
// GEMM1 + fused Q-RMSNorm epilogue.
// ---------------------------------------------------------------------------
__global__ __launch_bounds__(256)
void gemm_qrms(const short* __restrict__ A, const short* __restrict__ BT,
               bf16* __restrict__ qn, const float* __restrict__ qg,
               int M, int N, int K)
{
    GEMM_PROLOG_128
    const int h = (col0 + wc) >> 6;
    const float g0 = qg[l16], g1 = qg[16 + l16];
    #pragma unroll
    for (int mt = 0; mt < 4; ++mt) {
        float ss[4];
        #pragma unroll
        for (int r = 0; r < 4; ++r)
            ss[r] = acc[mt][0][r] * acc[mt][0][r] + acc[mt][1][r] * acc[mt][1][r]
                  + acc[mt][2][r] * acc[mt][2][r] + acc[mt][3][r] * acc[mt][3][r];
        #pragma unroll
        for (int off = 1; off < 16; off <<= 1)
            #pragma unroll
            for (int r = 0; r < 4; ++r) ss[r] += __shfl_xor(ss[r], off, 64);
        #pragma unroll
        for (int r = 0; r < 4; ++r) {
            const float inv = 0.125f / sqrtf(ss[r] * (1.0f / HD_) + EPS_);
            const int row = row0 + wr + mt * 16 + quad * 4 + r;
            const int b = row >> 11, t = row & 2047;
            bf16* op = qn + (((size_t)(b * HH + h)) * TT + t) * RP;
            op[l16]      = __float2bfloat16(g0 * acc[mt][0][r] * inv);
            op[16 + l16] = __float2bfloat16(g1 * acc[mt][1][r] * inv);
        }
    }
}

// ---------------------------------------------------------------------------
// GEMM4 + fused K-RMSNorm / V-split epilogue.
// ---------------------------------------------------------------------------
__global__ __launch_bounds__(256)
void gemm_kv(const short* __restrict__ A, const short* __restrict__ BT,
             bf16* __restrict__ kn, bf16* __restrict__ vb,
             const float* __restrict__ kg, int M, int N, int K)
{
    GEMM_PROLOG_128
    const int colbase = col0 + wc;
    if (colbase < 512) {                        // K-RMS path
        const int h0 = colbase >> 5;            // groups h0, h0+1
        const float g0 = kg[l16], g1 = kg[16 + l16];
        #pragma unroll
        for (int mt = 0; mt < 4; ++mt) {
            float s0[4], s1[4];
            #pragma unroll
            for (int r = 0; r < 4; ++r) {
                s0[r] = acc[mt][0][r] * acc[mt][0][r] + acc[mt][1][r] * acc[mt][1][r];
                s1[r] = acc[mt][2][r] * acc[mt][2][r] + acc[mt][3][r] * acc[mt][3][r];
            }
            #pragma unroll
            for (int off = 1; off < 16; off <<= 1)
                #pragma unroll
                for (int r = 0; r < 4; ++r) {
                    s0[r] += __shfl_xor(s0[r], off, 64);
                    s1[r] += __shfl_xor(s1[r], off, 64);
                }
            #pragma unroll
            for (int r = 0; r < 4; ++r) {
                const float i0 = 1.0f / sqrtf(s0[r] * (1.0f / RP) + EPS_);
                const float i1 = 1.0f / sqrtf(s1[r] * (1.0f / RP) + EPS_);
                const int row = row0 + wr + mt * 16 + quad * 4 + r;
                const int b = row >> 11, t = row & 2047;
                bf16* op0 = kn + (((size_t)(b * HH + h0)) * TT + t) * RP;
                bf16* op1 = kn + (((size_t)(b * HH + h0 + 1)) * TT + t) * RP;
                op0[l16]      = __float2bfloat16(g0 * acc[mt][0][r] * i0);
                op0[16 + l16] = __float2bfloat16(g1 * acc[mt][1][r] * i0);
                op1[l16]      = __float2bfloat16(g0 * acc[mt][2][r] * i1);
                op1[16 + l16] = __float2bfloat16(g1 * acc[mt][3][r] * i1);
            }
        }
    } else {                                     // V path
        const int h0 = (colbase - 512) >> 5;
        #pragma unroll
        for (int mt = 0; mt < 4; ++mt)
            #pragma unroll
            for (int r = 0; r < 4; ++r) {
                const int row = row0 + wr + mt * 16 + quad * 4 + r;
                const int b = row >> 11, t = row & 2047;
                bf16* op0 = vb + (((size_t)(b * HH + h0)) * TT + t) * RP;
                bf16* op1 = vb + (((size_t)(b * HH + h0 + 1)) * TT + t) * RP;
                op0[l16]      = __float2bfloat16(acc[mt][0][r]);
                op0[16 + l16] = __float2bfloat16(acc[mt][1][r]);
                op1[l16]      = __float2bfloat16(acc[mt][2][r]);
                op1[16 + l16] = __float2bfloat16(acc[mt][3][r]);
            }
    }
}

// ---------------------------------------------------------------------------
// 64x128-tile GEMM (gemm3: 8192x128, K=1024 -> 128 blocks).
// ---------------------------------------------------------------------------
__global__ __launch_bounds__(256)
void gemm_k64(const short* __restrict__ A, const short* __restrict__ BT,
              bf16* __restrict__ C, int M, int N, int K)
{
    __shared__ __align__(16) short As[64][32];
    __shared__ __align__(16) short Bs[128][32];
    const int tid  = threadIdx.x;
    const int wave = tid >> 6, lane = tid & 63;
    const int quad = lane >> 4, l16 = lane & 15;
    const int wr = (wave >> 1) * 32, wc = (wave & 1) * 64;
    const int row0 = blockIdx.y * 64, col0 = blockIdx.x * 128;
    const int srow = tid >> 2, scol = (tid & 3) * 8;

    char* lAs  = (char*)As + wave * 1024;
    char* lBs0 = (char*)Bs + wave * 1024;
    char* lBs1 = (char*)Bs + 4096 + wave * 1024;

    f32x4 acc[2][4];
    #pragma unroll
    for (int mt = 0; mt < 2; ++mt)
        #pragma unroll
        for (int nt = 0; nt < 4; ++nt)
            acc[mt][nt] = (f32x4){0.f, 0.f, 0.f, 0.f};

    for (int k0 = 0; k0 < K; k0 += 32) {
        const short* ga = A  + (size_t)(row0 + srow) * K + k0 + scol;
        const short* gb = BT + (size_t)(col0 + srow) * K + k0 + scol;
        __syncthreads();
        gl2lds16(ga,                  lAs);
        gl2lds16(gb,                  lBs0);
        gl2lds16(gb + (size_t)64 * K, lBs1);
        __syncthreads();

        bf16x8 af[2], bfv[4];
        #pragma unroll
        for (int mt = 0; mt < 2; ++mt)
            af[mt] = *(const bf16x8*)&As[wr + mt * 16 + l16][quad * 8];
        #pragma unroll
        for (int nt = 0; nt < 4; ++nt)
            bfv[nt] = *(const bf16x8*)&Bs[wc + nt * 16 + l16][quad * 8];
        #pragma unroll
        for (int mt = 0; mt < 2; ++mt)
            #pragma unroll
            for (int nt = 0; nt < 4; ++nt)
                acc[mt][nt] = __builtin_amdgcn_mfma_f32_16x16x32_bf16(
                    af[mt], bfv[nt], acc[mt][nt], 0, 0, 0);
    }

    #pragma unroll
    for (int mt = 0; mt < 2; ++mt)
        #pragma unroll
        for (int nt = 0; nt < 4; ++nt) {
            const int col = col0 + wc + nt * 16 + l16;
            #pragma unroll
            for (int r = 0; r < 4; ++r) {
                const int row = row0 + wr + mt * 16 + quad * 4 + r;
                C[(size_t)row * N + col] = __float2bfloat16(acc[mt][nt][r]);
            }
        }
}

// ---------------------------------------------------------------------------
// V transpose: vb (bh, t, 32) -> vT (bh, 32, 2048).
// ---------------------------------------------------------------------------
__global__ __launch_bounds__(256)
void vtrans_kernel(const bf16* __restrict__ vb, bf16* __restrict__ vT)
{
    __shared__ __align__(16) short tile[32][72];
    const int bh = blockIdx.y;
    const int t0 = blockIdx.x * 64;
    const int tid = threadIdx.x;
    const int tl = tid >> 2, c0 = (tid & 3) * 8;
    bf16x8 v = *(const bf16x8*)(vb + ((size_t)bh * TT + t0 + tl) * RP + c0);
    #pragma unroll
    for (int j = 0; j < 8; ++j) tile[c0 + j][tl] = v[j];
    __syncthreads();
    const int c = tid >> 3, tt = (tid & 7) * 8;
    bf16x8 o = *(const bf16x8*)&tile[c][tt];
    *(bf16x8*)(vT + ((size_t)bh * RP + c) * TT + t0 + tt) = o;
}

// ---------------------------------------------------------------------------
// Flash MFMA attention v4: 8-wave blocks, SPLIT-KV (balanced).
//  - All 8 waves work the same q-tile: wave w owns row-group rg=w&3
//    (16 q-rows) and KV-parity half=w>>2 (even/odd KV tiles).
//  - no-max softmax => order-free accumulation; parity partials (oacc,
//    lsum) combined per tile via LDS + __syncthreads.
//  - Per-wave steps = ceil((bx+1)/2) + ceil((32-bx)/2) ~ 17, balanced
//    across ALL waves of the grid -> true 32 waves/CU residency.
//  - K double-buffered in registers; V issued at step top.
//  - K-prefetch tail may read <=7KB past this bh's K slab (dead vb region;
//    reads only, never consumed). V reads exactly in-bounds.
// ---------------------------------------------------------------------------
struct __attribute__((aligned(8))) bf4 { bf16 v[4]; };

#define ATTN_STEP(KC, KN_, S0, S0N)                                             \
    {                                                                           \
        bf16x8 vc[4];                                                           \
        _Pragma("unroll")                                                       \
        for (int ks = 0; ks < 2; ++ks) {                                        \
            vc[2 * ks]     = *(const bf16x8*)(v0P + (S0) + ks * 32);            \
            vc[2 * ks + 1] = *(const bf16x8*)(v1P + (S0) + ks * 32);            \
        }                                                                       \
        _Pragma("unroll")                                                       \
        for (int sub = 0; sub < 4; ++sub)                                       \
            KN_[sub] = *(const bf16x8*)(kP + (size_t)((S0N) + sub * 16) * RP);  \
        f32x4 sc[4];                                                            \
        _Pragma("unroll")                                                       \
        for (int sub = 0; sub < 4; ++sub)                                       \
            sc[sub] = __builtin_amdgcn_mfma_f32_16x16x32_bf16(                  \
                KC[sub], qf, (f32x4){0.f, 0.f, 0.f, 0.f}, 0, 0, 0);             \
        if ((S0) + 63 > qbase) {                                                \
            const int qg_ = qbase + l16;                                        \
            _Pragma("unroll")                                                   \
            for (int sub = 0; sub < 4; ++sub)                                   \
                _Pragma("unroll")                                               \
                for (int r = 0; r < 4; ++r)                                     \
                    if ((S0) + sub * 16 + quad * 4 + r > qg_) sc[sub][r] = -1e30f; \
        }                                                                       \
        _Pragma("unroll")                                                       \
        for (int sub = 0; sub < 4; ++sub) {                                     \
            const float p0 = __expf(sc[sub][0]);                                \
            const float p1 = __expf(sc[sub][1]);                                \
            const float p2 = __expf(sc[sub][2]);                                \
            const float p3 = __expf(sc[sub][3]);                                \
            bf4 pk;                                                             \
            pk.v[0] = __float2bfloat16(p0);                                     \
            pk.v[1] = __float2bfloat16(p1);                                     \
            pk.v[2] = __float2bfloat16(p2);                                     \
            pk.v[3] = __float2bfloat16(p3);                                     \
            *(bf4*)&P_lds[w8][l16][sub * 16 + quad * 4] = pk;                   \
            lsum += (p0 + p1) + (p2 + p3);                                      \
        }                                                                       \
        _Pragma("unroll")                                                       \
        for (int ks = 0; ks < 2; ++ks) {                                        \
            bf16x8 pf = *(const bf16x8*)&P_lds[w8][l16][ks * 32 + quad * 8];    \
            oacc0 = __builtin_amdgcn_mfma_f32_16x16x32_bf16(pf, vc[2 * ks],     oacc0, 0, 0, 0); \
            oacc1 = __builtin_amdgcn_mfma_f32_16x16x32_bf16(pf, vc[2 * ks + 1], oacc1, 0, 0, 0); \
        }                                                                       \
    }

__global__ __launch_bounds__(512, 4)
void attn_mfma(const bf16* __restrict__ qn, const bf16* __restrict__ kn,
               const bf16* __restrict__ vT, bf16* __restrict__ att)
{
    __shared__ __align__(16) bf16 P_lds[8][16][72];
    __shared__ float comb[4][64][9];
    const int tid  = threadIdx.x;
    const int w8   = tid >> 6;                 // 0..7
    const int lane = tid & 63;
    const int quad = lane >> 4, l16 = lane & 15;
    const int rg   = w8 & 3;                   // row group
    const int half = w8 >> 2;                  // KV parity
    // XCD-aware bijective remap of (bx, bh):
    const int f  = (int)(blockIdx.y * 16 + blockIdx.x);   // 0..1023
    const int xr = f & 7, j = f >> 3;                      // j: 0..127
    const int bh = xr + 8 * (j >> 4);                      // bh%8 == xcd
    const int bx = j & 15;                                 // 0..15
    const int b = bh >> 4, h = bh & 15;

    const bf16* knb = kn + (size_t)bh * TT * RP;
    const bf16* vtb = vT + (size_t)bh * RP * TT;
    const bf16* kP  = knb + (size_t)l16 * RP + quad * 8;        // + s*RP
    const bf16* v0P = vtb + (size_t)l16 * TT + quad * 8;        // + s + ks*32
    const bf16* v1P = vtb + (size_t)(16 + l16) * TT + quad * 8;

    #pragma unroll 1
    for (int pi = 0; pi < 2; ++pi) {
        const int qt = pi ? (31 - bx) : bx;
        const int NT = qt + 1;
        const int qbase = qt * 64 + rg * 16;

        bf16x8 qf = *(const bf16x8*)(qn + ((size_t)bh * TT + qbase + l16) * RP + quad * 8);

        float lsum = 0.f;
        f32x4 oacc0 = (f32x4){0.f, 0.f, 0.f, 0.f};
        f32x4 oacc1 = (f32x4){0.f, 0.f, 0.f, 0.f};

        int st = half;                          // parity start
        if (st < NT) {
            int s0 = st * 64;
            bf16x8 kA[4], kB[4];
            #pragma unroll
            for (int sub = 0; sub < 4; ++sub)
                kA[sub] = *(const bf16x8*)(kP + (size_t)(s0 + sub * 16) * RP);
            while (true) {
                ATTN_STEP(kA, kB, s0, s0 + 128)
                st += 2; if (st >= NT) break;
                s0 += 128;
                ATTN_STEP(kB, kA, s0, s0 + 128)
                st += 2; if (st >= NT) break;
                s0 += 128;
            }
        }

        // ---- combine parity partials via LDS ----
        if (half) {
            float* cp = comb[rg][lane];
            #pragma unroll
            for (int r = 0; r < 4; ++r) { cp[r] = oacc0[r]; cp[4 + r] = oacc1[r]; }
            cp[8] = lsum;
        }
        __syncthreads();
        if (!half) {
            const float* cp = comb[rg][lane];
            #pragma unroll
            for (int r = 0; r < 4; ++r) { oacc0[r] += cp[r]; oacc1[r] += cp[4 + r]; }
            lsum += cp[8];
            lsum += __shfl_xor(lsum, 16, 64);
            lsum += __shfl_xor(lsum, 32, 64);
            #pragma unroll
            for (int r = 0; r < 4; ++r) {
                const float ls = __shfl(lsum, quad * 20 + r, 64);
                const float inv = 1.0f / ls;
                const int t = qbase + quad * 4 + r;
                bf16* op = att + ((size_t)(b * TT + t)) * 512 + h * 32;
                op[l16]      = __float2bfloat16(oacc0[r] * inv);
                op[16 + l16] = __float2bfloat16(oacc1[r] * inv);
            }
        }
        __syncthreads();                        // comb reuse for next pi
    }
}

// ---------------------------------------------------------------------------
// Workspace (BYTE offsets from base = d_ws + 64):
//   xb    bf16 [0, 16777216)            (dead after gemm_k64)
//   wqT   bf16 [16777216, 18874368)     (dead after gemm_qrms)
//   wkvT  bf16 [18874368, 19136512)     (dead after gemm_k64)
//   kvb   bf16 [19136512, 21233664)     (dead after gemm_kv)
//   att_b bf16 [0, 8388608)             (alias over dead xb)
//   vTb   bf16 [8388608, 16777216)      (alias over dead xb)
//   qn    bf16 [35913728, 44302336)
//   kn    bf16 [44302336, 52690944)     (attn K-prefetch tail -> vb, harmless)
//   vb    bf16 [52690944, 61079552)
//   wkwvT bf16 [61079552, 61341696)
//   woT   bf16 [61341696, 62390272)
// ---------------------------------------------------------------------------
extern "C" void kernel_launch(void* const* d_in, const int* in_sizes, int n_in,
                              void* d_out, int out_size, void* d_ws, size_t ws_size,
                              hipStream_t stream)
{
    float* out = (float*)d_out;
    const long long NOUT = (long long)BB * TT * DD;
    const int outgrid = (int)((NOUT + 255) / 256);

    static const long long expect[8] =
        {8388608, 1048576, 131072, 65536, 65536, 1048576, 64, 32};
    if (n_in != 8) {
        sentinel_kernel<<<outgrid, 256, 0, stream>>>(out, 20000.0f + 100.0f * n_in, NOUT);
        return;
    }
    for (int i = 0; i < 8; ++i) {
        if ((long long)in_sizes[i] != expect[i]) {
            sentinel_kernel<<<outgrid, 256, 0, stream>>>(out, 10000.0f + 1000.0f * i, NOUT);
            return;
        }
    }
    if (ws_size < 62914624ULL) {
        sentinel_kernel<<<outgrid, 256, 0, stream>>>(
            out, 30000.0f + (float)(ws_size >> 20), NOUT);
        return;
    }
    if (out_size != 8388608) {
        sentinel_kernel<<<outgrid, 256, 0, stream>>>(
            out, 512.0f * (1.0f + (float)(out_size >> 20)), NOUT);
        return;
    }

    const float* x   = (const float*)d_in[0];
    const float* Wq  = (const float*)d_in[1];
    const float* Wkv = (const float*)d_in[2];
    const float* Wk  = (const float*)d_in[3];
    const float* Wv  = (const float*)d_in[4];
    const float* Wo  = (const float*)d_in[5];
    const float* qg  = (const float*)d_in[6];
    const float* kg  = (const float*)d_in[7];

    char* base = (char*)d_ws + 64;
    bf16*  xb    = (bf16*)(base + 0);
    bf16*  wqT   = (bf16*)(base + 16777216);
    bf16*  wkvT  = (bf16*)(base + 18874368);
    bf16*  kvb   = (bf16*)(base + 19136512);
    bf16*  att_b = (bf16*)(base + 0);
    bf16*  vTb   = (bf16*)(base + 8388608);
    bf16*  qn    = (bf16*)(base + 35913728);
    bf16*  kn    = (bf16*)(base + 44302336);
    bf16*  vb    = (bf16*)(base + 52690944);
    bf16*  wkwvT = (bf16*)(base + 61079552);
    bf16*  woT   = (bf16*)(base + 61341696);

    const int BT = BB * TT;                    // 8192

    // 0. converts
    conv_x_kernel<<<outgrid / 4, 256, 0, stream>>>(x, xb, NOUT / 4);
    conv_trans_kernel<<<dim3(16, 16), 256, 0, stream>>>(Wq, wqT, 1024, 1024);
    conv_trans_kernel<<<dim3(2, 16), 256, 0, stream>>>(Wkv, wkvT, 1024, 128);
    conv_wkwv_kernel<<<512, 256, 0, stream>>>(Wk, Wv, wkwvT);
    conv_woT_kernel<<<dim3(16, 8), 256, 0, stream>>>(Wo, woT);

    // 1. qn = rmsnorm(xb @ Wq)[:, :32] * 0.125 (fused GEMM+RMS epilogue)
    gemm_qrms<<<dim3(8, 64), 256, 0, stream>>>(
        (const short*)xb, (const short*)wqT, qn, qg, BT, DD, DD);
    // 2. kvb = xb @ Wkv (64-row tiles -> 128 blocks), 8192x128, K=1024
    gemm_k64<<<dim3(1, 128), 256, 0, stream>>>(
        (const short*)xb, (const short*)wkvT, kvb, BT, LAT_, DD);
    // 3. kn/vb = fused(kvb @ [Wk|Wv]) (GEMM + K-RMS/V-split epilogue)
    gemm_kv<<<dim3(8, 64), 256, 0, stream>>>(
        (const short*)kvb, (const short*)wkwvT, kn, vb, kg, BT, 2 * 512, LAT_);
    // 4. vT = transpose(vb)
    vtrans_kernel<<<dim3(32, 64), 256, 0, stream>>>(vb, vTb);
    // 5. flash MFMA attention (8-wave split-KV, XCD swizzle)
    attn_mfma<<<dim3(16, 64), 512, 0, stream>>>(qn, kn, vTb, att_b);
    // 6. out = att_b @ Wo_remap (MFMA), 8192x1024, K=512
    gemm_mfma<float><<<dim3(8, 64), 256, 0, stream>>>(
        (const short*)att_b, (const short*)woT, out, BT, DD, 512);
}

// Round 9
// 242.449 us; speedup vs baseline: 1.2025x; 1.2025x over previous
//
#include <hip/hip_runtime.h>
#include <hip/hip_bf16.h>
#include <math.h>

using bf16 = __hip_bfloat16;
typedef __attribute__((ext_vector_type(8))) short bf16x8;
typedef __attribute__((ext_vector_type(4))) float f32x4;

#define BB   4
#define TT   2048
#define DD   1024
#define HH   16
#define HD_  64
#define LAT_ 128
#define RP   32
#define EPS_ 1e-6f

static __device__ __forceinline__ void stf(float* p, float v) { *p = v; }
static __device__ __forceinline__ void stf(bf16* p, float v) { *p = __float2bfloat16(v); }

// global -> LDS 16B DMA (wave-uniform LDS base + lane*16)
static __device__ __forceinline__ void gl2lds16(const void* g, void* l)
{
    __builtin_amdgcn_global_load_lds(
        (const __attribute__((address_space(1))) void*)g,
        (__attribute__((address_space(3))) void*)l, 16, 0, 0);
}

__global__ __launch_bounds__(256)
void sentinel_kernel(float* __restrict__ out, float val, long long n)
{
    long long i = (long long)blockIdx.x * 256 + threadIdx.x;
    if (i < n) out[i] = val;
}

// ---------------------------------------------------------------------------
// Converters
// ---------------------------------------------------------------------------
__global__ __launch_bounds__(256)
void conv_x_kernel(const float* __restrict__ x, bf16* __restrict__ xb, long long n4)
{
    long long i = (long long)blockIdx.x * 256 + threadIdx.x;
    if (i >= n4) return;
    float4 v = *(const float4*)(x + i * 4);
    union { bf16 h[4]; uint2 u; } o;
    o.h[0] = __float2bfloat16(v.x);
    o.h[1] = __float2bfloat16(v.y);
    o.h[2] = __float2bfloat16(v.z);
    o.h[3] = __float2bfloat16(v.w);
    *(uint2*)(xb + i * 4) = o.u;
}

// Tiled transpose-convert: W (K x N fp32 row-major) -> WT (N x K bf16).
__global__ __launch_bounds__(256)
void conv_trans_kernel(const float* __restrict__ W, bf16* __restrict__ WT,
                       int K, int N)
{
    __shared__ __align__(16) bf16 t[64][72];
    const int k0 = blockIdx.y * 64, n0 = blockIdx.x * 64;
    const int tid = threadIdx.x;
    const int r = tid >> 2, c0 = (tid & 3) * 16;
    const float* src = W + (size_t)(k0 + r) * N + n0 + c0;
    #pragma unroll
    for (int j = 0; j < 16; j += 4) {
        float4 v = *(const float4*)(src + j);
        t[c0 + j + 0][r] = __float2bfloat16(v.x);
        t[c0 + j + 1][r] = __float2bfloat16(v.y);
        t[c0 + j + 2][r] = __float2bfloat16(v.z);
        t[c0 + j + 3][r] = __float2bfloat16(v.w);
    }
    __syncthreads();
    const int rr = tid >> 2, cc = (tid & 3) * 16;
    bf16* dst = WT + (size_t)(n0 + rr) * K + k0 + cc;
    *(bf16x8*)dst       = *(const bf16x8*)&t[rr][cc];
    *(bf16x8*)(dst + 8) = *(const bf16x8*)&t[rr][cc + 8];
}

// [Wk | Wv] (each 128x512) -> WT (1024 x 128).
__global__ __launch_bounds__(256)
void conv_wkwv_kernel(const float* __restrict__ Wk, const float* __restrict__ Wv,
                      bf16* __restrict__ WT)
{
    int idx = blockIdx.x * 256 + threadIdx.x;      // 128*1024
    if (idx >= 128 * 1024) return;
    int k = idx >> 10, n = idx & 1023;
    float v = (n < 512) ? Wk[k * 512 + n] : Wv[k * 512 + (n - 512)];
    WT[(size_t)n * 128 + k] = __float2bfloat16(v);
}

// Wo (1024x1024) -> woT (1024 x 512) tiled transpose with row remap.
__global__ __launch_bounds__(256)
void conv_woT_kernel(const float* __restrict__ Wo, bf16* __restrict__ WT)
{
    __shared__ __align__(16) bf16 t[64][72];
    const int mm0 = blockIdx.y * 64, n0 = blockIdx.x * 64;
    const int tid = threadIdx.x;
    const int r = tid >> 2, c0 = (tid & 3) * 16;
    const int mm = mm0 + r;
    const int row = ((mm >> 5) << 6) | (mm & 31);
    const float* src = Wo + (size_t)row * 1024 + n0 + c0;
    #pragma unroll
    for (int j = 0; j < 16; j += 4) {
        float4 v = *(const float4*)(src + j);
        t[c0 + j + 0][r] = __float2bfloat16(v.x);
        t[c0 + j + 1][r] = __float2bfloat16(v.y);
        t[c0 + j + 2][r] = __float2bfloat16(v.z);
        t[c0 + j + 3][r] = __float2bfloat16(v.w);
    }
    __syncthreads();
    const int rr = tid >> 2, cc = (tid & 3) * 16;
    bf16* dst = WT + (size_t)(n0 + rr) * 512 + mm0 + cc;
    *(bf16x8*)dst       = *(const bf16x8*)&t[rr][cc];
    *(bf16x8*)(dst + 8) = *(const bf16x8*)&t[rr][cc + 8];
}

// ---------------------------------------------------------------------------
// MFMA GEMM with global_load_lds staging. C[M,N] = A @ B, A bf16 (M x K)
// row-major, BT bf16 (N x K) row-major. 128x128 tile, BK=32.
// Fragment maps (HW-verified): A[m=lane&15][k=quad*8+j],
// BT[n=lane&15][k=quad*8+j], C/D row=quad*4+reg, col=lane&15.
// ---------------------------------------------------------------------------
#define GEMM_PROLOG_128 \
    __shared__ __align__(16) short As[128][32]; \
    __shared__ __align__(16) short Bs[128][32]; \
    const int tid  = threadIdx.x; \
    const int wave = tid >> 6, lane = tid & 63; \
    const int quad = lane >> 4, l16 = lane & 15; \
    const int wr = (wave >> 1) * 64, wc = (wave & 1) * 64; \
    const int row0 = blockIdx.y * 128, col0 = blockIdx.x * 128; \
    const int srow = tid >> 2, scol = (tid & 3) * 8; \
    char* lAs0 = (char*)As + wave * 1024; \
    char* lAs1 = (char*)As + 4096 + wave * 1024; \
    char* lBs0 = (char*)Bs + wave * 1024; \
    char* lBs1 = (char*)Bs + 4096 + wave * 1024; \
    f32x4 acc[4][4]; \
    _Pragma("unroll") \
    for (int mt = 0; mt < 4; ++mt) \
        _Pragma("unroll") \
        for (int nt = 0; nt < 4; ++nt) \
            acc[mt][nt] = (f32x4){0.f, 0.f, 0.f, 0.f}; \
    for (int k0 = 0; k0 < K; k0 += 32) { \
        const short* ga = A  + (size_t)(row0 + srow) * K + k0 + scol; \
        const short* gb = BT + (size_t)(col0 + srow) * K + k0 + scol; \
        __syncthreads(); \
        gl2lds16(ga,                  lAs0); \
        gl2lds16(ga + (size_t)64 * K, lAs1); \
        gl2lds16(gb,                  lBs0); \
        gl2lds16(gb + (size_t)64 * K, lBs1); \
        __syncthreads(); \
        bf16x8 af[4], bfv[4]; \
        _Pragma("unroll") \
        for (int mt = 0; mt < 4; ++mt) \
            af[mt] = *(const bf16x8*)&As[wr + mt * 16 + l16][quad * 8]; \
        _Pragma("unroll") \
        for (int nt = 0; nt < 4; ++nt) \
            bfv[nt] = *(const bf16x8*)&Bs[wc + nt * 16 + l16][quad * 8]; \
        _Pragma("unroll") \
        for (int mt = 0; mt < 4; ++mt) \
            _Pragma("unroll") \
            for (int nt = 0; nt < 4; ++nt) \
                acc[mt][nt] = __builtin_amdgcn_mfma_f32_16x16x32_bf16( \
                    af[mt], bfv[nt], acc[mt][nt], 0, 0, 0); \
    }

template <typename OT>
__global__ __launch_bounds__(256)
void gemm_mfma(const short* __restrict__ A, const short* __restrict__ BT,
               OT* __restrict__ C, int M, int N, int K)
{
    GEMM_PROLOG_128
    #pragma unroll
    for (int mt = 0; mt < 4; ++mt)
        #pragma unroll
        for (int nt = 0; nt < 4; ++nt) {
            const int col = col0 + wc + nt * 16 + l16;
            #pragma unroll
            for (int r = 0; r < 4; ++r) {
                const int row = row0 + wr + mt * 16 + quad * 4 + r;
                stf(C + (size_t)row * N + col, acc[mt][nt][r]);
            }
        }
}

// ---------------------------------------------------------------------------
// GEMM1 + fused Q-RMSNorm epilogue.
// ---------------------------------------------------------------------------
__global__ __launch_bounds__(256)
void gemm_qrms(const short* __restrict__ A, const short* __restrict__ BT,
               bf16* __restrict__ qn, const float* __restrict__ qg,
               int M, int N, int K)
{
    GEMM_PROLOG_128
    const int h = (col0 + wc) >> 6;
    const float g0 = qg[l16], g1 = qg[16 + l16];
    #pragma unroll
    for (int mt = 0; mt < 4; ++mt) {
        float ss[4];
        #pragma unroll
        for (int r = 0; r < 4; ++r)
            ss[r] = acc[mt][0][r] * acc[mt][0][r] + acc[mt][1][r] * acc[mt][1][r]
                  + acc[mt][2][r] * acc[mt][2][r] + acc[mt][3][r] * acc[mt][3][r];
        #pragma unroll
        for (int off = 1; off < 16; off <<= 1)
            #pragma unroll
            for (int r = 0; r < 4; ++r) ss[r] += __shfl_xor(ss[r], off, 64);
        #pragma unroll
        for (int r = 0; r < 4; ++r) {
            const float inv = 0.125f / sqrtf(ss[r] * (1.0f / HD_) + EPS_);
            const int row = row0 + wr + mt * 16 + quad * 4 + r;
            const int b = row >> 11, t = row & 2047;
            bf16* op = qn + (((size_t)(b * HH + h)) * TT + t) * RP;
            op[l16]      = __float2bfloat16(g0 * acc[mt][0][r] * inv);
            op[16 + l16] = __float2bfloat16(g1 * acc[mt][1][r] * inv);
        }
    }
}

// ---------------------------------------------------------------------------
// GEMM4 + fused K-RMSNorm / V-split epilogue.
// ---------------------------------------------------------------------------
__global__ __launch_bounds__(256)
void gemm_kv(const short* __restrict__ A, const short* __restrict__ BT,
             bf16* __restrict__ kn, bf16* __restrict__ vb,
             const float* __restrict__ kg, int M, int N, int K)
{
    GEMM_PROLOG_128
    const int colbase = col0 + wc;
    if (colbase < 512) {                        // K-RMS path
        const int h0 = colbase >> 5;            // groups h0, h0+1
        const float g0 = kg[l16], g1 = kg[16 + l16];
        #pragma unroll
        for (int mt = 0; mt < 4; ++mt) {
            float s0[4], s1[4];
            #pragma unroll
            for (int r = 0; r < 4; ++r) {
                s0[r] = acc[mt][0][r] * acc[mt][0][r] + acc[mt][1][r] * acc[mt][1][r];
                s1[r] = acc[mt][2][r] * acc[mt][2][r] + acc[mt][3][r] * acc[mt][3][r];
            }
            #pragma unroll
            for (int off = 1; off < 16; off <<= 1)
                #pragma unroll
                for (int r = 0; r < 4; ++r) {
                    s0[r] += __shfl_xor(s0[r], off, 64);
                    s1[r] += __shfl_xor(s1[r], off, 64);
                }
            #pragma unroll
            for (int r = 0; r < 4; ++r) {
                const float i0 = 1.0f / sqrtf(s0[r] * (1.0f / RP) + EPS_);
                const float i1 = 1.0f / sqrtf(s1[r] * (1.0f / RP) + EPS_);
                const int row = row0 + wr + mt * 16 + quad * 4 + r;
                const int b = row >> 11, t = row & 2047;
                bf16* op0 = kn + (((size_t)(b * HH + h0)) * TT + t) * RP;
                bf16* op1 = kn + (((size_t)(b * HH + h0 + 1)) * TT + t) * RP;
                op0[l16]      = __float2bfloat16(g0 * acc[mt][0][r] * i0);
                op0[16 + l16] = __float2bfloat16(g1 * acc[mt][1][r] * i0);
                op1[l16]      = __float2bfloat16(g0 * acc[mt][2][r] * i1);
                op1[16 + l16] = __float2bfloat16(g1 * acc[mt][3][r] * i1);
            }
        }
    } else {                                     // V path
        const int h0 = (colbase - 512) >> 5;
        #pragma unroll
        for (int mt = 0; mt < 4; ++mt)
            #pragma unroll
            for (int r = 0; r < 4; ++r) {
                const int row = row0 + wr + mt * 16 + quad * 4 + r;
                const int b = row >> 11, t = row & 2047;
                bf16* op0 = vb + (((size_t)(b * HH + h0)) * TT + t) * RP;
                bf16* op1 = vb + (((size_t)(b * HH + h0 + 1)) * TT + t) * RP;
                op0[l16]      = __float2bfloat16(acc[mt][0][r]);
                op0[16 + l16] = __float2bfloat16(acc[mt][1][r]);
                op1[l16]      = __float2bfloat16(acc[mt][2][r]);
                op1[16 + l16] = __float2bfloat16(acc[mt][3][r]);
            }
    }
}

// ---------------------------------------------------------------------------
// 64x128-tile GEMM (gemm3: 8192x128, K=1024 -> 128 blocks).
// ---------------------------------------------------------------------------
__global__ __launch_bounds__(256)
void gemm_k64(const short* __restrict__ A, const short* __restrict__ BT,
              bf16* __restrict__ C, int M, int N, int K)
{
    __shared__ __align__(16) short As[64][32];
    __shared__ __align__(16) short Bs[128][32];
    const int tid  = threadIdx.x;
    const int wave = tid >> 6, lane = tid & 63;
    const int quad = lane >> 4, l16 = lane & 15;
    const int wr = (wave >> 1) * 32, wc = (wave & 1) * 64;
    const int row0 = blockIdx.y * 64, col0 = blockIdx.x * 128;
    const int srow = tid >> 2, scol = (tid & 3) * 8;

    char* lAs  = (char*)As + wave * 1024;
    char* lBs0 = (char*)Bs + wave * 1024;
    char* lBs1 = (char*)Bs + 4096 + wave * 1024;

    f32x4 acc[2][4];
    #pragma unroll
    for (int mt = 0; mt < 2; ++mt)
        #pragma unroll
        for (int nt = 0; nt < 4; ++nt)
            acc[mt][nt] = (f32x4){0.f, 0.f, 0.f, 0.f};

    for (int k0 = 0; k0 < K; k0 += 32) {
        const short* ga = A  + (size_t)(row0 + srow) * K + k0 + scol;
        const short* gb = BT + (size_t)(col0 + srow) * K + k0 + scol;
        __syncthreads();
        gl2lds16(ga,                  lAs);
        gl2lds16(gb,                  lBs0);
        gl2lds16(gb + (size_t)64 * K, lBs1);
        __syncthreads();

        bf16x8 af[2], bfv[4];
        #pragma unroll
        for (int mt = 0; mt < 2; ++mt)
            af[mt] = *(const bf16x8*)&As[wr + mt * 16 + l16][quad * 8];
        #pragma unroll
        for (int nt = 0; nt < 4; ++nt)
            bfv[nt] = *(const bf16x8*)&Bs[wc + nt * 16 + l16][quad * 8];
        #pragma unroll
        for (int mt = 0; mt < 2; ++mt)
            #pragma unroll
            for (int nt = 0; nt < 4; ++nt)
                acc[mt][nt] = __builtin_amdgcn_mfma_f32_16x16x32_bf16(
                    af[mt], bfv[nt], acc[mt][nt], 0, 0, 0);
    }

    #pragma unroll
    for (int mt = 0; mt < 2; ++mt)
        #pragma unroll
        for (int nt = 0; nt < 4; ++nt) {
            const int col = col0 + wc + nt * 16 + l16;
            #pragma unroll
            for (int r = 0; r < 4; ++r) {
                const int row = row0 + wr + mt * 16 + quad * 4 + r;
                C[(size_t)row * N + col] = __float2bfloat16(acc[mt][nt][r]);
            }
        }
}

// ---------------------------------------------------------------------------
// V transpose: vb (bh, t, 32) -> vT (bh, 32, 2048).
// ---------------------------------------------------------------------------
__global__ __launch_bounds__(256)
void vtrans_kernel(const bf16* __restrict__ vb, bf16* __restrict__ vT)
{
    __shared__ __align__(16) short tile[32][72];
    const int bh = blockIdx.y;
    const int t0 = blockIdx.x * 64;
    const int tid = threadIdx.x;
    const int tl = tid >> 2, c0 = (tid & 3) * 8;
    bf16x8 v = *(const bf16x8*)(vb + ((size_t)bh * TT + t0 + tl) * RP + c0);
    #pragma unroll
    for (int j = 0; j < 8; ++j) tile[c0 + j][tl] = v[j];
    __syncthreads();
    const int c = tid >> 3, tt = (tid & 7) * 8;
    bf16x8 o = *(const bf16x8*)&tile[c][tt];
    *(bf16x8*)(vT + ((size_t)bh * RP + c) * TT + t0 + tt) = o;
}

// ---------------------------------------------------------------------------
// Flash MFMA attention v5: COOPERATIVE LDS STAGING (m97 GEMM pattern).
//  - 512-thread blocks (8 waves), each block owns a 128-row q-tile; wave w8
//    owns rows [qt*128 + w8*16, +16).
//  - Per 64-row KV step: block stages K(64x32) + V^T(32x64) = 8 KB via ONE
//    global_load_lds per wave (waves 0-3 stage K, 4-7 stage V), 2-barrier
//    synced; all waves compute from the shared LDS copy. This cuts VMEM
//    request count 8x vs per-wave fragment loads (the R4-R8 invariant
//    suspect: TA/L1 request serialization).
//  - Tile pairing (bx <-> 15-bx) -> every block exactly 34 steps, uniform.
//  - Fully-masked steps: exp(-1e30)=0 contributes nothing; no divergence,
//    barriers stay uniform.
//  - no-max softmax (scores bounded by RMS-norm), swapped-QK layout,
//    XCD swizzle (all 8 q-tile blocks of a bh on one XCD).
// ---------------------------------------------------------------------------
struct __attribute__((aligned(8))) bf4 { bf16 v[4]; };

__global__ __launch_bounds__(512, 4)
void attn_mfma(const bf16* __restrict__ qn, const bf16* __restrict__ kn,
               const bf16* __restrict__ vT, bf16* __restrict__ att)
{
    __shared__ __align__(16) short Ks[64][32];        // 4 KB
    __shared__ __align__(16) short Vs[32][64];        // 4 KB
    __shared__ __align__(16) bf16 P_lds[8][16][72];   // 18 KB
    const int tid  = threadIdx.x;
    const int w8   = tid >> 6, lane = tid & 63;
    const int quad = lane >> 4, l16 = lane & 15;
    // XCD-aware bijective remap: f -> (bx 0..7, bh 0..63), bh%8 == xcd
    const int f  = (int)(blockIdx.y * 8 + blockIdx.x);     // 0..511
    const int xr = f & 7, j = f >> 3;                       // j: 0..63
    const int bx = j & 7;
    const int bh = xr + 8 * (j >> 3);
    const int b = bh >> 4, h = bh & 15;

    const bf16* knb = kn + (size_t)bh * TT * RP;
    const bf16* vtb = vT + (size_t)bh * RP * TT;

    // staging: wave-uniform LDS base + lane*16 (HW rule); chunk = w8*64+lane
    // K chunk c (0..255): row=c>>2, col=(c&3)*8 ; addr += s0*RP per step
    // V chunk c (0..255): row=c>>3, col=(c&7)*8 ; addr += s0 per step
    const bool isK = (w8 < 4);
    const int  cK = tid;                // valid when isK
    const int  cV = tid - 256;
    const bf16* sBase = isK
        ? knb + (size_t)(cK >> 2) * RP + (cK & 3) * 8
        : vtb + (size_t)(cV >> 3) * TT + (cV & 7) * 8;
    const int  sMult = isK ? RP : 1;
    char* ldsDst = isK ? ((char*)Ks + w8 * 1024)
                       : ((char*)Vs + (w8 - 4) * 1024);

    #pragma unroll 1
    for (int pi = 0; pi < 2; ++pi) {
        const int qt = pi ? (15 - bx) : bx;          // 128-row q-tile, 0..15
        const int NT = 2 * qt + 2;                   // 64-row KV steps
        const int qbase = qt * 128 + w8 * 16;

        bf16x8 qf = *(const bf16x8*)(qn + ((size_t)bh * TT + qbase + l16) * RP + quad * 8);

        float lsum = 0.f;
        f32x4 oacc0 = (f32x4){0.f, 0.f, 0.f, 0.f};
        f32x4 oacc1 = (f32x4){0.f, 0.f, 0.f, 0.f};

        for (int st = 0; st < NT; ++st) {
            const int s0 = st * 64;
            __syncthreads();                         // prev step's reads done
            gl2lds16(sBase + (size_t)s0 * sMult, ldsDst);
            __syncthreads();                         // staged data ready

            // ---- swapped QK^T from LDS: D[s_local=quad*4+r][q=l16] ----
            f32x4 sc[4];
            #pragma unroll
            for (int sub = 0; sub < 4; ++sub) {
                bf16x8 kf = *(const bf16x8*)&Ks[sub * 16 + l16][quad * 8];
                sc[sub] = __builtin_amdgcn_mfma_f32_16x16x32_bf16(
                    kf, qf, (f32x4){0.f, 0.f, 0.f, 0.f}, 0, 0, 0);
            }

            // ---- causal mask (also zeroes fully-masked steps) ----
            if (s0 + 63 > qbase) {
                const int qg_ = qbase + l16;
                #pragma unroll
                for (int sub = 0; sub < 4; ++sub)
                    #pragma unroll
                    for (int r = 0; r < 4; ++r)
                        if (s0 + sub * 16 + quad * 4 + r > qg_) sc[sub][r] = -1e30f;
            }

            // ---- p = exp(sc), pack -> P_lds; per-lane partial sum ----
            #pragma unroll
            for (int sub = 0; sub < 4; ++sub) {
                const float p0 = __expf(sc[sub][0]);
                const float p1 = __expf(sc[sub][1]);
                const float p2 = __expf(sc[sub][2]);
                const float p3 = __expf(sc[sub][3]);
                bf4 pk;
                pk.v[0] = __float2bfloat16(p0);
                pk.v[1] = __float2bfloat16(p1);
                pk.v[2] = __float2bfloat16(p2);
                pk.v[3] = __float2bfloat16(p3);
                *(bf4*)&P_lds[w8][l16][sub * 16 + quad * 4] = pk;
                lsum += (p0 + p1) + (p2 + p3);
            }

            // ---- PV from LDS: D[q_local][c] ----
            #pragma unroll
            for (int ks = 0; ks < 2; ++ks) {
                bf16x8 pf  = *(const bf16x8*)&P_lds[w8][l16][ks * 32 + quad * 8];
                bf16x8 vf0 = *(const bf16x8*)&Vs[l16][ks * 32 + quad * 8];
                bf16x8 vf1 = *(const bf16x8*)&Vs[16 + l16][ks * 32 + quad * 8];
                oacc0 = __builtin_amdgcn_mfma_f32_16x16x32_bf16(pf, vf0, oacc0, 0, 0, 0);
                oacc1 = __builtin_amdgcn_mfma_f32_16x16x32_bf16(pf, vf1, oacc1, 0, 0, 0);
            }
        }

        // ---- epilogue (per wave; no cross-wave combine) ----
        lsum += __shfl_xor(lsum, 16, 64);
        lsum += __shfl_xor(lsum, 32, 64);
        #pragma unroll
        for (int r = 0; r < 4; ++r) {
            const float ls = __shfl(lsum, quad * 20 + r, 64);
            const float inv = 1.0f / ls;
            const int t = qbase + quad * 4 + r;
            bf16* op = att + ((size_t)(b * TT + t)) * 512 + h * 32;
            op[l16]      = __float2bfloat16(oacc0[r] * inv);
            op[16 + l16] = __float2bfloat16(oacc1[r] * inv);
        }
    }
}

// ---------------------------------------------------------------------------
// Workspace (BYTE offsets from base = d_ws + 64):
//   xb    bf16 [0, 16777216)            (dead after gemm_k64)
//   wqT   bf16 [16777216, 18874368)     (dead after gemm_qrms)
//   wkvT  bf16 [18874368, 19136512)     (dead after gemm_k64)
//   kvb   bf16 [19136512, 21233664)     (dead after gemm_kv)
//   att_b bf16 [0, 8388608)             (alias over dead xb)
//   vTb   bf16 [8388608, 16777216)      (alias over dead xb)
//   qn    bf16 [35913728, 44302336)
//   kn    bf16 [44302336, 52690944)
//   vb    bf16 [52690944, 61079552)
//   wkwvT bf16 [61079552, 61341696)
//   woT   bf16 [61341696, 62390272)
// ---------------------------------------------------------------------------
extern "C" void kernel_launch(void* const* d_in, const int* in_sizes, int n_in,
                              void* d_out, int out_size, void* d_ws, size_t ws_size,
                              hipStream_t stream)
{
    float* out = (float*)d_out;
    const long long NOUT = (long long)BB * TT * DD;
    const int outgrid = (int)((NOUT + 255) / 256);

    static const long long expect[8] =
        {8388608, 1048576, 131072, 65536, 65536, 1048576, 64, 32};
    if (n_in != 8) {
        sentinel_kernel<<<outgrid, 256, 0, stream>>>(out, 20000.0f + 100.0f * n_in, NOUT);
        return;
    }
    for (int i = 0; i < 8; ++i) {
        if ((long long)in_sizes[i] != expect[i]) {
            sentinel_kernel<<<outgrid, 256, 0, stream>>>(out, 10000.0f + 1000.0f * i, NOUT);
            return;
        }
    }
    if (ws_size < 62914624ULL) {
        sentinel_kernel<<<outgrid, 256, 0, stream>>>(
            out, 30000.0f + (float)(ws_size >> 20), NOUT);
        return;
    }
    if (out_size != 8388608) {
        sentinel_kernel<<<outgrid, 256, 0, stream>>>(
            out, 512.0f * (1.0f + (float)(out_size >> 20)), NOUT);
        return;
    }

    const float* x   = (const float*)d_in[0];
    const float* Wq  = (const float*)d_in[1];
    const float* Wkv = (const float*)d_in[2];
    const float* Wk  = (const float*)d_in[3];
    const float* Wv  = (const float*)d_in[4];
    const float* Wo  = (const float*)d_in[5];
    const float* qg  = (const float*)d_in[6];
    const float* kg  = (const float*)d_in[7];

    char* base = (char*)d_ws + 64;
    bf16*  xb    = (bf16*)(base + 0);
    bf16*  wqT   = (bf16*)(base + 16777216);
    bf16*  wkvT  = (bf16*)(base + 18874368);
    bf16*  kvb   = (bf16*)(base + 19136512);
    bf16*  att_b = (bf16*)(base + 0);
    bf16*  vTb   = (bf16*)(base + 8388608);
    bf16*  qn    = (bf16*)(base + 35913728);
    bf16*  kn    = (bf16*)(base + 44302336);
    bf16*  vb    = (bf16*)(base + 52690944);
    bf16*  wkwvT = (bf16*)(base + 61079552);
    bf16*  woT   = (bf16*)(base + 61341696);

    const int BT = BB * TT;                    // 8192

    // 0. converts
    conv_x_kernel<<<outgrid / 4, 256, 0, stream>>>(x, xb, NOUT / 4);
    conv_trans_kernel<<<dim3(16, 16), 256, 0, stream>>>(Wq, wqT, 1024, 1024);
    conv_trans_kernel<<<dim3(2, 16), 256, 0, stream>>>(Wkv, wkvT, 1024, 128);
    conv_wkwv_kernel<<<512, 256, 0, stream>>>(Wk, Wv, wkwvT);
    conv_woT_kernel<<<dim3(16, 8), 256, 0, stream>>>(Wo, woT);

    // 1. qn = rmsnorm(xb @ Wq)[:, :32] * 0.125 (fused GEMM+RMS epilogue)
    gemm_qrms<<<dim3(8, 64), 256, 0, stream>>>(
        (const short*)xb, (const short*)wqT, qn, qg, BT, DD, DD);
    // 2. kvb = xb @ Wkv (64-row tiles -> 128 blocks), 8192x128, K=1024
    gemm_k64<<<dim3(1, 128), 256, 0, stream>>>(
        (const short*)xb, (const short*)wkvT, kvb, BT, LAT_, DD);
    // 3. kn/vb = fused(kvb @ [Wk|Wv]) (GEMM + K-RMS/V-split epilogue)
    gemm_kv<<<dim3(8, 64), 256, 0, stream>>>(
        (const short*)kvb, (const short*)wkwvT, kn, vb, kg, BT, 2 * 512, LAT_);
    // 4. vT = transpose(vb)
    vtrans_kernel<<<dim3(32, 64), 256, 0, stream>>>(vb, vTb);
    // 5. flash MFMA attention (cooperative LDS staging, paired 128-row tiles)
    attn_mfma<<<dim3(8, 64), 512, 0, stream>>>(qn, kn, vTb, att_b);
    // 6. out = att_b @ Wo_remap (MFMA), 8192x1024, K=512
    gemm_mfma<float><<<dim3(8, 64), 256, 0, stream>>>(
        (const short*)att_b, (const short*)woT, out, BT, DD, 512);
}

// Round 10
// 235.350 us; speedup vs baseline: 1.2388x; 1.0302x over previous
//
#include <hip/hip_runtime.h>
#include <hip/hip_bf16.h>
#include <math.h>

using bf16 = __hip_bfloat16;
typedef __attribute__((ext_vector_type(8))) short bf16x8;
typedef __attribute__((ext_vector_type(4))) float f32x4;

#define BB   4
#define TT   2048
#define DD   1024
#define HH   16
#define HD_  64
#define LAT_ 128
#define RP   32
#define EPS_ 1e-6f

static __device__ __forceinline__ void stf(float* p, float v) { *p = v; }
static __device__ __forceinline__ void stf(bf16* p, float v) { *p = __float2bfloat16(v); }

// global -> LDS 16B DMA (wave-uniform LDS base + lane*16)
static __device__ __forceinline__ void gl2lds16(const void* g, void* l)
{
    __builtin_amdgcn_global_load_lds(
        (const __attribute__((address_space(1))) void*)g,
        (__attribute__((address_space(3))) void*)l, 16, 0, 0);
}

__global__ __launch_bounds__(256)
void sentinel_kernel(float* __restrict__ out, float val, long long n)
{
    long long i = (long long)blockIdx.x * 256 + threadIdx.x;
    if (i < n) out[i] = val;
}

// ---------------------------------------------------------------------------
// Converters
// ---------------------------------------------------------------------------
__global__ __launch_bounds__(256)
void conv_x_kernel(const float* __restrict__ x, bf16* __restrict__ xb, long long n4)
{
    long long i = (long long)blockIdx.x * 256 + threadIdx.x;
    if (i >= n4) return;
    float4 v = *(const float4*)(x + i * 4);
    union { bf16 h[4]; uint2 u; } o;
    o.h[0] = __float2bfloat16(v.x);
    o.h[1] = __float2bfloat16(v.y);
    o.h[2] = __float2bfloat16(v.z);
    o.h[3] = __float2bfloat16(v.w);
    *(uint2*)(xb + i * 4) = o.u;
}

// Tiled transpose-convert: W (K x N fp32 row-major) -> WT (N x K bf16).
__global__ __launch_bounds__(256)
void conv_trans_kernel(const float* __restrict__ W, bf16* __restrict__ WT,
                       int K, int N)
{
    __shared__ __align__(16) bf16 t[64][72];
    const int k0 = blockIdx.y * 64, n0 = blockIdx.x * 64;
    const int tid = threadIdx.x;
    const int r = tid >> 2, c0 = (tid & 3) * 16;
    const float* src = W + (size_t)(k0 + r) * N + n0 + c0;
    #pragma unroll
    for (int j = 0; j < 16; j += 4) {
        float4 v = *(const float4*)(src + j);
        t[c0 + j + 0][r] = __float2bfloat16(v.x);
        t[c0 + j + 1][r] = __float2bfloat16(v.y);
        t[c0 + j + 2][r] = __float2bfloat16(v.z);
        t[c0 + j + 3][r] = __float2bfloat16(v.w);
    }
    __syncthreads();
    const int rr = tid >> 2, cc = (tid & 3) * 16;
    bf16* dst = WT + (size_t)(n0 + rr) * K + k0 + cc;
    *(bf16x8*)dst       = *(const bf16x8*)&t[rr][cc];
    *(bf16x8*)(dst + 8) = *(const bf16x8*)&t[rr][cc + 8];
}

// [Wk | Wv] (each 128x512) -> WT (1024 x 128).
__global__ __launch_bounds__(256)
void conv_wkwv_kernel(const float* __restrict__ Wk, const float* __restrict__ Wv,
                      bf16* __restrict__ WT)
{
    int idx = blockIdx.x * 256 + threadIdx.x;      // 128*1024
    if (idx >= 128 * 1024) return;
    int k = idx >> 10, n = idx & 1023;
    float v = (n < 512) ? Wk[k * 512 + n] : Wv[k * 512 + (n - 512)];
    WT[(size_t)n * 128 + k] = __float2bfloat16(v);
}

// Wo (1024x1024) -> woT (1024 x 512) tiled transpose with row remap.
__global__ __launch_bounds__(256)
void conv_woT_kernel(const float* __restrict__ Wo, bf16* __restrict__ WT)
{
    __shared__ __align__(16) bf16 t[64][72];
    const int mm0 = blockIdx.y * 64, n0 = blockIdx.x * 64;
    const int tid = threadIdx.x;
    const int r = tid >> 2, c0 = (tid & 3) * 16;
    const int mm = mm0 + r;
    const int row = ((mm >> 5) << 6) | (mm & 31);
    const float* src = Wo + (size_t)row * 1024 + n0 + c0;
    #pragma unroll
    for (int j = 0; j < 16; j += 4) {
        float4 v = *(const float4*)(src + j);
        t[c0 + j + 0][r] = __float2bfloat16(v.x);
        t[c0 + j + 1][r] = __float2bfloat16(v.y);
        t[c0 + j + 2][r] = __float2bfloat16(v.z);
        t[c0 + j + 3][r] = __float2bfloat16(v.w);
    }
    __syncthreads();
    const int rr = tid >> 2, cc = (tid & 3) * 16;
    bf16* dst = WT + (size_t)(n0 + rr) * 512 + mm0 + cc;
    *(bf16x8*)dst       = *(const bf16x8*)&t[rr][cc];
    *(bf16x8*)(dst + 8) = *(const bf16x8*)&t[rr][cc + 8];
}

// ---------------------------------------------------------------------------
// MFMA GEMM with global_load_lds staging. C[M,N] = A @ B, A bf16 (M x K)
// row-major, BT bf16 (N x K) row-major. 128x128 tile, BK=32.
// Fragment maps (HW-verified): A[m=lane&15][k=quad*8+j],
// BT[n=lane&15][k=quad*8+j], C/D row=quad*4+reg, col=lane&15.
// ---------------------------------------------------------------------------
#define GEMM_PROLOG_128 \
    __shared__ __align__(16) short As[128][32]; \
    __shared__ __align__(16) short Bs[128][32]; \
    const int tid  = threadIdx.x; \
    const int wave = tid >> 6, lane = tid & 63; \
    const int quad = lane >> 4, l16 = lane & 15; \
    const int wr = (wave >> 1) * 64, wc = (wave & 1) * 64; \
    const int row0 = blockIdx.y * 128, col0 = blockIdx.x * 128; \
    const int srow = tid >> 2, scol = (tid & 3) * 8; \
    char* lAs0 = (char*)As + wave * 1024; \
    char* lAs1 = (char*)As + 4096 + wave * 1024; \
    char* lBs0 = (char*)Bs + wave * 1024; \
    char* lBs1 = (char*)Bs + 4096 + wave * 1024; \
    f32x4 acc[4][4]; \
    _Pragma("unroll") \
    for (int mt = 0; mt < 4; ++mt) \
        _Pragma("unroll") \
        for (int nt = 0; nt < 4; ++nt) \
            acc[mt][nt] = (f32x4){0.f, 0.f, 0.f, 0.f}; \
    for (int k0 = 0; k0 < K; k0 += 32) { \
        const short* ga = A  + (size_t)(row0 + srow) * K + k0 + scol; \
        const short* gb = BT + (size_t)(col0 + srow) * K + k0 + scol; \
        __syncthreads(); \
        gl2lds16(ga,                  lAs0); \
        gl2lds16(ga + (size_t)64 * K, lAs1); \
        gl2lds16(gb,                  lBs0); \
        gl2lds16(gb + (size_t)64 * K, lBs1); \
        __syncthreads(); \
        bf16x8 af[4], bfv[4]; \
        _Pragma("unroll") \
        for (int mt = 0; mt < 4; ++mt) \
            af[mt] = *(const bf16x8*)&As[wr + mt * 16 + l16][quad * 8]; \
        _Pragma("unroll") \
        for (int nt = 0; nt < 4; ++nt) \
            bfv[nt] = *(const bf16x8*)&Bs[wc + nt * 16 + l16][quad * 8]; \
        _Pragma("unroll") \
        for (int mt = 0; mt < 4; ++mt) \
            _Pragma("unroll") \
            for (int nt = 0; nt < 4; ++nt) \
                acc[mt][nt] = __builtin_amdgcn_mfma_f32_16x16x32_bf16( \
                    af[mt], bfv[nt], acc[mt][nt], 0, 0, 0); \
    }

template <typename OT>
__global__ __launch_bounds__(256)
void gemm_mfma(const short* __restrict__ A, const short* __restrict__ BT,
               OT* __restrict__ C, int M, int N, int K)
{
    GEMM_PROLOG_128
    #pragma unroll
    for (int mt = 0; mt < 4; ++mt)
        #pragma unroll
        for (int nt = 0; nt < 4; ++nt) {
            const int col = col0 + wc + nt * 16 + l16;
            #pragma unroll
            for (int r = 0; r < 4; ++r) {
                const int row = row0 + wr + mt * 16 + quad * 4 + r;
                stf(C + (size_t)row * N + col, acc[mt][nt][r]);
            }
        }
}

// ---------------------------------------------------------------------------
// GEMM1 + fused Q-RMSNorm epilogue.
// ---------------------------------------------------------------------------
__global__ __launch_bounds__(256)
void gemm_qrms(const short* __restrict__ A, const short* __restrict__ BT,
               bf16* __restrict__ qn, const float* __restrict__ qg,
               int M, int N, int K)
{
    GEMM_PROLOG_128
    const int h = (col0 + wc) >> 6;
    const float g0 = qg[l16], g1 = qg[16 + l16];
    #pragma unroll
    for (int mt = 0; mt < 4; ++mt) {
        float ss[4];
        #pragma unroll
        for (int r = 0; r < 4; ++r)
            ss[r] = acc[mt][0][r] * acc[mt][0][r] + acc[mt][1][r] * acc[mt][1][r]
                  + acc[mt][2][r] * acc[mt][2][r] + acc[mt][3][r] * acc[mt][3][r];
        #pragma unroll
        for (int off = 1; off < 16; off <<= 1)
            #pragma unroll
            for (int r = 0; r < 4; ++r) ss[r] += __shfl_xor(ss[r], off, 64);
        #pragma unroll
        for (int r = 0; r < 4; ++r) {
            const float inv = 0.125f / sqrtf(ss[r] * (1.0f / HD_) + EPS_);
            const int row = row0 + wr + mt * 16 + quad * 4 + r;
            const int b = row >> 11, t = row & 2047;
            bf16* op = qn + (((size_t)(b * HH + h)) * TT + t) * RP;
            op[l16]      = __float2bfloat16(g0 * acc[mt][0][r] * inv);
            op[16 + l16] = __float2bfloat16(g1 * acc[mt][1][r] * inv);
        }
    }
}

// ---------------------------------------------------------------------------
// GEMM4 + fused K-RMSNorm / V-split epilogue.
// ---------------------------------------------------------------------------
__global__ __launch_bounds__(256)
void gemm_kv(const short* __restrict__ A, const short* __restrict__ BT,
             bf16* __restrict__ kn, bf16* __restrict__ vb,
             const float* __restrict__ kg, int M, int N, int K)
{
    GEMM_PROLOG_128
    const int colbase = col0 + wc;
    if (colbase < 512) {                        // K-RMS path
        const int h0 = colbase >> 5;            // groups h0, h0+1
        const float g0 = kg[l16], g1 = kg[16 + l16];
        #pragma unroll
        for (int mt = 0; mt < 4; ++mt) {
            float s0[4], s1[4];
            #pragma unroll
            for (int r = 0; r < 4; ++r) {
                s0[r] = acc[mt][0][r] * acc[mt][0][r] + acc[mt][1][r] * acc[mt][1][r];
                s1[r] = acc[mt][2][r] * acc[mt][2][r] + acc[mt][3][r] * acc[mt][3][r];
            }
            #pragma unroll
            for (int off = 1; off < 16; off <<= 1)
                #pragma unroll
                for (int r = 0; r < 4; ++r) {
                    s0[r] += __shfl_xor(s0[r], off, 64);
                    s1[r] += __shfl_xor(s1[r], off, 64);
                }
            #pragma unroll
            for (int r = 0; r < 4; ++r) {
                const float i0 = 1.0f / sqrtf(s0[r] * (1.0f / RP) + EPS_);
                const float i1 = 1.0f / sqrtf(s1[r] * (1.0f / RP) + EPS_);
                const int row = row0 + wr + mt * 16 + quad * 4 + r;
                const int b = row >> 11, t = row & 2047;
                bf16* op0 = kn + (((size_t)(b * HH + h0)) * TT + t) * RP;
                bf16* op1 = kn + (((size_t)(b * HH + h0 + 1)) * TT + t) * RP;
                op0[l16]      = __float2bfloat16(g0 * acc[mt][0][r] * i0);
                op0[16 + l16] = __float2bfloat16(g1 * acc[mt][1][r] * i0);
                op1[l16]      = __float2bfloat16(g0 * acc[mt][2][r] * i1);
                op1[16 + l16] = __float2bfloat16(g1 * acc[mt][3][r] * i1);
            }
        }
    } else {                                     // V path
        const int h0 = (colbase - 512) >> 5;
        #pragma unroll
        for (int mt = 0; mt < 4; ++mt)
            #pragma unroll
            for (int r = 0; r < 4; ++r) {
                const int row = row0 + wr + mt * 16 + quad * 4 + r;
                const int b = row >> 11, t = row & 2047;
                bf16* op0 = vb + (((size_t)(b * HH + h0)) * TT + t) * RP;
                bf16* op1 = vb + (((size_t)(b * HH + h0 + 1)) * TT + t) * RP;
                op0[l16]      = __float2bfloat16(acc[mt][0][r]);
                op0[16 + l16] = __float2bfloat16(acc[mt][1][r]);
                op1[l16]      = __float2bfloat16(acc[mt][2][r]);
                op1[16 + l16] = __float2bfloat16(acc[mt][3][r]);
            }
    }
}

// ---------------------------------------------------------------------------
// 64x128-tile GEMM (gemm3: 8192x128, K=1024 -> 128 blocks).
// ---------------------------------------------------------------------------
__global__ __launch_bounds__(256)
void gemm_k64(const short* __restrict__ A, const short* __restrict__ BT,
              bf16* __restrict__ C, int M, int N, int K)
{
    __shared__ __align__(16) short As[64][32];
    __shared__ __align__(16) short Bs[128][32];
    const int tid  = threadIdx.x;
    const int wave = tid >> 6, lane = tid & 63;
    const int quad = lane >> 4, l16 = lane & 15;
    const int wr = (wave >> 1) * 32, wc = (wave & 1) * 64;
    const int row0 = blockIdx.y * 64, col0 = blockIdx.x * 128;
    const int srow = tid >> 2, scol = (tid & 3) * 8;

    char* lAs  = (char*)As + wave * 1024;
    char* lBs0 = (char*)Bs + wave * 1024;
    char* lBs1 = (char*)Bs + 4096 + wave * 1024;

    f32x4 acc[2][4];
    #pragma unroll
    for (int mt = 0; mt < 2; ++mt)
        #pragma unroll
        for (int nt = 0; nt < 4; ++nt)
            acc[mt][nt] = (f32x4){0.f, 0.f, 0.f, 0.f};

    for (int k0 = 0; k0 < K; k0 += 32) {
        const short* ga = A  + (size_t)(row0 + srow) * K + k0 + scol;
        const short* gb = BT + (size_t)(col0 + srow) * K + k0 + scol;
        __syncthreads();
        gl2lds16(ga,                  lAs);
        gl2lds16(gb,                  lBs0);
        gl2lds16(gb + (size_t)64 * K, lBs1);
        __syncthreads();

        bf16x8 af[2], bfv[4];
        #pragma unroll
        for (int mt = 0; mt < 2; ++mt)
            af[mt] = *(const bf16x8*)&As[wr + mt * 16 + l16][quad * 8];
        #pragma unroll
        for (int nt = 0; nt < 4; ++nt)
            bfv[nt] = *(const bf16x8*)&Bs[wc + nt * 16 + l16][quad * 8];
        #pragma unroll
        for (int mt = 0; mt < 2; ++mt)
            #pragma unroll
            for (int nt = 0; nt < 4; ++nt)
                acc[mt][nt] = __builtin_amdgcn_mfma_f32_16x16x32_bf16(
                    af[mt], bfv[nt], acc[mt][nt], 0, 0, 0);
    }

    #pragma unroll
    for (int mt = 0; mt < 2; ++mt)
        #pragma unroll
        for (int nt = 0; nt < 4; ++nt) {
            const int col = col0 + wc + nt * 16 + l16;
            #pragma unroll
            for (int r = 0; r < 4; ++r) {
                const int row = row0 + wr + mt * 16 + quad * 4 + r;
                C[(size_t)row * N + col] = __float2bfloat16(acc[mt][nt][r]);
            }
        }
}

// ---------------------------------------------------------------------------
// V transpose: vb (bh, t, 32) -> vT (bh, 32, 2048).
// ---------------------------------------------------------------------------
__global__ __launch_bounds__(256)
void vtrans_kernel(const bf16* __restrict__ vb, bf16* __restrict__ vT)
{
    __shared__ __align__(16) short tile[32][72];
    const int bh = blockIdx.y;
    const int t0 = blockIdx.x * 64;
    const int tid = threadIdx.x;
    const int tl = tid >> 2, c0 = (tid & 3) * 8;
    bf16x8 v = *(const bf16x8*)(vb + ((size_t)bh * TT + t0 + tl) * RP + c0);
    #pragma unroll
    for (int j = 0; j < 8; ++j) tile[c0 + j][tl] = v[j];
    __syncthreads();
    const int c = tid >> 3, tt = (tid & 7) * 8;
    bf16x8 o = *(const bf16x8*)&tile[c][tt];
    *(bf16x8*)(vT + ((size_t)bh * RP + c) * TT + t0 + tt) = o;
}

// ---------------------------------------------------------------------------
// Flash MFMA attention v6: cooperative LDS staging + XOR bank swizzle.
//  R9 counters: SQ_LDS_BANK_CONFLICT 12.26M/dispatch ~ 20 us of LDS-pipe
//  serialization. Cause: Ks row stride 64B -> 8-way conflict on QK frag
//  read; Vs row stride 128B (=32 banks) -> 16-way on PV V-read.
//  Fix (rule #21: both-sides-or-neither with global_load_lds): LDS dest
//  stays LINEAR; 16B-slot XOR swizzle applied to the GLOBAL source addr
//  and the LDS READ addr with the same involution:
//    K: slot ^= (row>>1)&3   (src chunk c: gslot=(c&3)^((c>>3)&3))
//    V: slot ^= row&7        (src chunk c: gslot=(c&7)^((c>>3)&7))
//  -> both reads become 2-way (free, m136). P_lds (144B stride) already
//  2-way, untouched.
// ---------------------------------------------------------------------------
struct __attribute__((aligned(8))) bf4 { bf16 v[4]; };

__global__ __launch_bounds__(512, 4)
void attn_mfma(const bf16* __restrict__ qn, const bf16* __restrict__ kn,
               const bf16* __restrict__ vT, bf16* __restrict__ att)
{
    __shared__ __align__(16) short KsF[64 * 32];      // 4 KB, swizzled slots
    __shared__ __align__(16) short VsF[32 * 64];      // 4 KB, swizzled slots
    __shared__ __align__(16) bf16 P_lds[8][16][72];   // 18 KB
    const int tid  = threadIdx.x;
    const int w8   = tid >> 6, lane = tid & 63;
    const int quad = lane >> 4, l16 = lane & 15;
    // XCD-aware bijective remap: f -> (bx 0..7, bh 0..63), bh%8 == xcd
    const int f  = (int)(blockIdx.y * 8 + blockIdx.x);     // 0..511
    const int xr = f & 7, j = f >> 3;                       // j: 0..63
    const int bx = j & 7;
    const int bh = xr + 8 * (j >> 3);
    const int b = bh >> 4, h = bh & 15;

    const bf16* knb = kn + (size_t)bh * TT * RP;
    const bf16* vtb = vT + (size_t)bh * RP * TT;

    // staging map (LDS dest linear: chunk c -> byte c*16 within K/V region)
    // K chunk c (=tid, waves 0-3): row=c>>2, lds slot=c&3 holds global slot
    //   (c&3)^((c>>3)&3)  [slot_g = slot_lds ^ (row>>1)&3]
    // V chunk c (=tid-256, waves 4-7): row=c>>3, lds slot=c&7 holds global
    //   slot (c&7)^((c>>3)&7)
    const bool isK = (w8 < 4);
    const int  cK = tid;
    const int  cV = tid - 256;
    const bf16* sBase = isK
        ? knb + (size_t)(cK >> 2) * RP + ((cK & 3) ^ ((cK >> 3) & 3)) * 8
        : vtb + (size_t)(cV >> 3) * TT + ((cV & 7) ^ ((cV >> 3) & 7)) * 8;
    const int  sMult = isK ? RP : 1;
    char* ldsDst = isK ? ((char*)KsF + w8 * 1024)
                       : ((char*)VsF + (w8 - 4) * 1024);

    // swizzled read offsets (in shorts)
    //   K frag (row=sub*16+l16, slot=quad): row*32 + (quad^((l16>>1)&3))*8
    const int kslot = ((l16 >> 1) & 3);
    //   V frag (row=l16 or 16+l16, slot=ks*4+quad): row*64 + (slot^(l16&7))*8
    const int vswz = (l16 & 7);

    #pragma unroll 1
    for (int pi = 0; pi < 2; ++pi) {
        const int qt = pi ? (15 - bx) : bx;          // 128-row q-tile, 0..15
        const int NT = 2 * qt + 2;                   // 64-row KV steps
        const int qbase = qt * 128 + w8 * 16;

        bf16x8 qf = *(const bf16x8*)(qn + ((size_t)bh * TT + qbase + l16) * RP + quad * 8);

        float lsum = 0.f;
        f32x4 oacc0 = (f32x4){0.f, 0.f, 0.f, 0.f};
        f32x4 oacc1 = (f32x4){0.f, 0.f, 0.f, 0.f};

        for (int st = 0; st < NT; ++st) {
            const int s0 = st * 64;
            __syncthreads();                         // prev step's reads done
            gl2lds16(sBase + (size_t)s0 * sMult, ldsDst);
            __syncthreads();                         // staged data ready

            // ---- swapped QK^T from swizzled LDS: D[s_local][q=l16] ----
            f32x4 sc[4];
            #pragma unroll
            for (int sub = 0; sub < 4; ++sub) {
                bf16x8 kf = *(const bf16x8*)&KsF[(sub * 16 + l16) * 32
                                                 + ((quad ^ kslot) * 8)];
                sc[sub] = __builtin_amdgcn_mfma_f32_16x16x32_bf16(
                    kf, qf, (f32x4){0.f, 0.f, 0.f, 0.f}, 0, 0, 0);
            }

            // ---- causal mask (also zeroes fully-masked steps) ----
            if (s0 + 63 > qbase) {
                const int qg_ = qbase + l16;
                #pragma unroll
                for (int sub = 0; sub < 4; ++sub)
                    #pragma unroll
                    for (int r = 0; r < 4; ++r)
                        if (s0 + sub * 16 + quad * 4 + r > qg_) sc[sub][r] = -1e30f;
            }

            // ---- p = exp(sc), pack -> P_lds; per-lane partial sum ----
            #pragma unroll
            for (int sub = 0; sub < 4; ++sub) {
                const float p0 = __expf(sc[sub][0]);
                const float p1 = __expf(sc[sub][1]);
                const float p2 = __expf(sc[sub][2]);
                const float p3 = __expf(sc[sub][3]);
                bf4 pk;
                pk.v[0] = __float2bfloat16(p0);
                pk.v[1] = __float2bfloat16(p1);
                pk.v[2] = __float2bfloat16(p2);
                pk.v[3] = __float2bfloat16(p3);
                *(bf4*)&P_lds[w8][l16][sub * 16 + quad * 4] = pk;
                lsum += (p0 + p1) + (p2 + p3);
            }

            // ---- PV from swizzled LDS: D[q_local][c] ----
            #pragma unroll
            for (int ks = 0; ks < 2; ++ks) {
                bf16x8 pf  = *(const bf16x8*)&P_lds[w8][l16][ks * 32 + quad * 8];
                bf16x8 vf0 = *(const bf16x8*)&VsF[l16 * 64
                                + (((ks * 4 + quad) ^ vswz) * 8)];
                bf16x8 vf1 = *(const bf16x8*)&VsF[(16 + l16) * 64
                                + (((ks * 4 + quad) ^ vswz) * 8)];
                oacc0 = __builtin_amdgcn_mfma_f32_16x16x32_bf16(pf, vf0, oacc0, 0, 0, 0);
                oacc1 = __builtin_amdgcn_mfma_f32_16x16x32_bf16(pf, vf1, oacc1, 0, 0, 0);
            }
        }

        // ---- epilogue (per wave) ----
        lsum += __shfl_xor(lsum, 16, 64);
        lsum += __shfl_xor(lsum, 32, 64);
        #pragma unroll
        for (int r = 0; r < 4; ++r) {
            const float ls = __shfl(lsum, quad * 20 + r, 64);
            const float inv = 1.0f / ls;
            const int t = qbase + quad * 4 + r;
            bf16* op = att + ((size_t)(b * TT + t)) * 512 + h * 32;
            op[l16]      = __float2bfloat16(oacc0[r] * inv);
            op[16 + l16] = __float2bfloat16(oacc1[r] * inv);
        }
    }
}

// ---------------------------------------------------------------------------
// Workspace (BYTE offsets from base = d_ws + 64):
//   xb    bf16 [0, 16777216)            (dead after gemm_k64)
//   wqT   bf16 [16777216, 18874368)     (dead after gemm_qrms)
//   wkvT  bf16 [18874368, 19136512)     (dead after gemm_k64)
//   kvb   bf16 [19136512, 21233664)     (dead after gemm_kv)
//   att_b bf16 [0, 8388608)             (alias over dead xb)
//   vTb   bf16 [8388608, 16777216)      (alias over dead xb)
//   qn    bf16 [35913728, 44302336)
//   kn    bf16 [44302336, 52690944)
//   vb    bf16 [52690944, 61079552)
//   wkwvT bf16 [61079552, 61341696)
//   woT   bf16 [61341696, 62390272)
// ---------------------------------------------------------------------------
extern "C" void kernel_launch(void* const* d_in, const int* in_sizes, int n_in,
                              void* d_out, int out_size, void* d_ws, size_t ws_size,
                              hipStream_t stream)
{
    float* out = (float*)d_out;
    const long long NOUT = (long long)BB * TT * DD;
    const int outgrid = (int)((NOUT + 255) / 256);

    static const long long expect[8] =
        {8388608, 1048576, 131072, 65536, 65536, 1048576, 64, 32};
    if (n_in != 8) {
        sentinel_kernel<<<outgrid, 256, 0, stream>>>(out, 20000.0f + 100.0f * n_in, NOUT);
        return;
    }
    for (int i = 0; i < 8; ++i) {
        if ((long long)in_sizes[i] != expect[i]) {
            sentinel_kernel<<<outgrid, 256, 0, stream>>>(out, 10000.0f + 1000.0f * i, NOUT);
            return;
        }
    }
    if (ws_size < 62914624ULL) {
        sentinel_kernel<<<outgrid, 256, 0, stream>>>(
            out, 30000.0f + (float)(ws_size >> 20), NOUT);
        return;
    }
    if (out_size != 8388608) {
        sentinel_kernel<<<outgrid, 256, 0, stream>>>(
            out, 512.0f * (1.0f + (float)(out_size >> 20)), NOUT);
        return;
    }

    const float* x   = (const float*)d_in[0];
    const float* Wq  = (const float*)d_in[1];
    const float* Wkv = (const float*)d_in[2];
    const float* Wk  = (const float*)d_in[3];
    const float* Wv  = (const float*)d_in[4];
    const float* Wo  = (const float*)d_in[5];
    const float* qg  = (const float*)d_in[6];
    const float* kg  = (const float*)d_in[7];

    char* base = (char*)d_ws + 64;
    bf16*  xb    = (bf16*)(base + 0);
    bf16*  wqT   = (bf16*)(base + 16777216);
    bf16*  wkvT  = (bf16*)(base + 18874368);
    bf16*  kvb   = (bf16*)(base + 19136512);
    bf16*  att_b = (bf16*)(base + 0);
    bf16*  vTb   = (bf16*)(base + 8388608);
    bf16*  qn    = (bf16*)(base + 35913728);
    bf16*  kn    = (bf16*)(base + 44302336);
    bf16*  vb    = (bf16*)(base + 52690944);
    bf16*  wkwvT = (bf16*)(base + 61079552);
    bf16*  woT   = (bf16*)(base + 61341696);

    const int BT = BB * TT;                    // 8192

    // 0. converts
    conv_x_kernel<<<outgrid / 4, 256, 0, stream>>>(x, xb, NOUT / 4);
    conv_trans_kernel<<<dim3(16, 16), 256, 0, stream>>>(Wq, wqT, 1024, 1024);
    conv_trans_kernel<<<dim3(2, 16), 256, 0, stream>>>(Wkv, wkvT, 1024, 128);
    conv_wkwv_kernel<<<512, 256, 0, stream>>>(Wk, Wv, wkwvT);
    conv_woT_kernel<<<dim3(16, 8), 256, 0, stream>>>(Wo, woT);

    // 1. qn = rmsnorm(xb @ Wq)[:, :32] * 0.125 (fused GEMM+RMS epilogue)
    gemm_qrms<<<dim3(8, 64), 256, 0, stream>>>(
        (const short*)xb, (const short*)wqT, qn, qg, BT, DD, DD);
    // 2. kvb = xb @ Wkv (64-row tiles -> 128 blocks), 8192x128, K=1024
    gemm_k64<<<dim3(1, 128), 256, 0, stream>>>(
        (const short*)xb, (const short*)wkvT, kvb, BT, LAT_, DD);
    // 3. kn/vb = fused(kvb @ [Wk|Wv]) (GEMM + K-RMS/V-split epilogue)
    gemm_kv<<<dim3(8, 64), 256, 0, stream>>>(
        (const short*)kvb, (const short*)wkwvT, kn, vb, kg, BT, 2 * 512, LAT_);
    // 4. vT = transpose(vb)
    vtrans_kernel<<<dim3(32, 64), 256, 0, stream>>>(vb, vTb);
    // 5. flash MFMA attention (cooperative LDS staging + XOR swizzle)
    attn_mfma<<<dim3(8, 64), 512, 0, stream>>>(qn, kn, vTb, att_b);
    // 6. out = att_b @ Wo_remap (MFMA), 8192x1024, K=512
    gemm_mfma<float><<<dim3(8, 64), 256, 0, stream>>>(
        (const short*)att_b, (const short*)woT, out, BT, DD, 512);
}

// Round 11
// 230.223 us; speedup vs baseline: 1.2664x; 1.0223x over previous
//
#include <hip/hip_runtime.h>
#include <hip/hip_bf16.h>
#include <math.h>

using bf16 = __hip_bfloat16;
typedef __attribute__((ext_vector_type(8))) short bf16x8;
typedef __attribute__((ext_vector_type(4))) float f32x4;

#define BB   4
#define TT   2048
#define DD   1024
#define HH   16
#define HD_  64
#define LAT_ 128
#define RP   32
#define EPS_ 1e-6f

static __device__ __forceinline__ void stf(float* p, float v) { *p = v; }
static __device__ __forceinline__ void stf(bf16* p, float v) { *p = __float2bfloat16(v); }

// global -> LDS 16B DMA (wave-uniform LDS base + lane*16)
static __device__ __forceinline__ void gl2lds16(const void* g, void* l)
{
    __builtin_amdgcn_global_load_lds(
        (const __attribute__((address_space(1))) void*)g,
        (__attribute__((address_space(3))) void*)l, 16, 0, 0);
}

__global__ __launch_bounds__(256)
void sentinel_kernel(float* __restrict__ out, float val, long long n)
{
    long long i = (long long)blockIdx.x * 256 + threadIdx.x;
    if (i < n) out[i] = val;
}

// ---------------------------------------------------------------------------
// Converters
// ---------------------------------------------------------------------------
__global__ __launch_bounds__(256)
void conv_x_kernel(const float* __restrict__ x, bf16* __restrict__ xb, long long n4)
{
    long long i = (long long)blockIdx.x * 256 + threadIdx.x;
    if (i >= n4) return;
    float4 v = *(const float4*)(x + i * 4);
    union { bf16 h[4]; uint2 u; } o;
    o.h[0] = __float2bfloat16(v.x);
    o.h[1] = __float2bfloat16(v.y);
    o.h[2] = __float2bfloat16(v.z);
    o.h[3] = __float2bfloat16(v.w);
    *(uint2*)(xb + i * 4) = o.u;
}

// Tiled transpose-convert: W (K x N fp32 row-major) -> WT (N x K bf16).
__global__ __launch_bounds__(256)
void conv_trans_kernel(const float* __restrict__ W, bf16* __restrict__ WT,
                       int K, int N)
{
    __shared__ __align__(16) bf16 t[64][72];
    const int k0 = blockIdx.y * 64, n0 = blockIdx.x * 64;
    const int tid = threadIdx.x;
    const int r = tid >> 2, c0 = (tid & 3) * 16;
    const float* src = W + (size_t)(k0 + r) * N + n0 + c0;
    #pragma unroll
    for (int j = 0; j < 16; j += 4) {
        float4 v = *(const float4*)(src + j);
        t[c0 + j + 0][r] = __float2bfloat16(v.x);
        t[c0 + j + 1][r] = __float2bfloat16(v.y);
        t[c0 + j + 2][r] = __float2bfloat16(v.z);
        t[c0 + j + 3][r] = __float2bfloat16(v.w);
    }
    __syncthreads();
    const int rr = tid >> 2, cc = (tid & 3) * 16;
    bf16* dst = WT + (size_t)(n0 + rr) * K + k0 + cc;
    *(bf16x8*)dst       = *(const bf16x8*)&t[rr][cc];
    *(bf16x8*)(dst + 8) = *(const bf16x8*)&t[rr][cc + 8];
}

// [Wk | Wv] (each 128x512) -> WT (1024 x 128).
__global__ __launch_bounds__(256)
void conv_wkwv_kernel(const float* __restrict__ Wk, const float* __restrict__ Wv,
                      bf16* __restrict__ WT)
{
    int idx = blockIdx.x * 256 + threadIdx.x;      // 128*1024
    if (idx >= 128 * 1024) return;
    int k = idx >> 10, n = idx & 1023;
    float v = (n < 512) ? Wk[k * 512 + n] : Wv[k * 512 + (n - 512)];
    WT[(size_t)n * 128 + k] = __float2bfloat16(v);
}

// Wo (1024x1024) -> woT (1024 x 512) tiled transpose with row remap.
__global__ __launch_bounds__(256)
void conv_woT_kernel(const float* __restrict__ Wo, bf16* __restrict__ WT)
{
    __shared__ __align__(16) bf16 t[64][72];
    const int mm0 = blockIdx.y * 64, n0 = blockIdx.x * 64;
    const int tid = threadIdx.x;
    const int r = tid >> 2, c0 = (tid & 3) * 16;
    const int mm = mm0 + r;
    const int row = ((mm >> 5) << 6) | (mm & 31);
    const float* src = Wo + (size_t)row * 1024 + n0 + c0;
    #pragma unroll
    for (int j = 0; j < 16; j += 4) {
        float4 v = *(const float4*)(src + j);
        t[c0 + j + 0][r] = __float2bfloat16(v.x);
        t[c0 + j + 1][r] = __float2bfloat16(v.y);
        t[c0 + j + 2][r] = __float2bfloat16(v.z);
        t[c0 + j + 3][r] = __float2bfloat16(v.w);
    }
    __syncthreads();
    const int rr = tid >> 2, cc = (tid & 3) * 16;
    bf16* dst = WT + (size_t)(n0 + rr) * 512 + mm0 + cc;
    *(bf16x8*)dst       = *(const bf16x8*)&t[rr][cc];
    *(bf16x8*)(dst + 8) = *(const bf16x8*)&t[rr][cc + 8];
}

// ---------------------------------------------------------------------------
// MFMA GEMM with global_load_lds staging. C[M,N] = A @ B, A bf16 (M x K)
// row-major, BT bf16 (N x K) row-major. 128x128 tile, BK=32.
// Fragment maps (HW-verified): A[m=lane&15][k=quad*8+j],
// BT[n=lane&15][k=quad*8+j], C/D row=quad*4+reg, col=lane&15.
// ---------------------------------------------------------------------------
#define GEMM_PROLOG_128 \
    __shared__ __align__(16) short As[128][32]; \
    __shared__ __align__(16) short Bs[128][32]; \
    const int tid  = threadIdx.x; \
    const int wave = tid >> 6, lane = tid & 63; \
    const int quad = lane >> 4, l16 = lane & 15; \
    const int wr = (wave >> 1) * 64, wc = (wave & 1) * 64; \
    const int row0 = blockIdx.y * 128, col0 = blockIdx.x * 128; \
    const int srow = tid >> 2, scol = (tid & 3) * 8; \
    char* lAs0 = (char*)As + wave * 1024; \
    char* lAs1 = (char*)As + 4096 + wave * 1024; \
    char* lBs0 = (char*)Bs + wave * 1024; \
    char* lBs1 = (char*)Bs + 4096 + wave * 1024; \
    f32x4 acc[4][4]; \
    _Pragma("unroll") \
    for (int mt = 0; mt < 4; ++mt) \
        _Pragma("unroll") \
        for (int nt = 0; nt < 4; ++nt) \
            acc[mt][nt] = (f32x4){0.f, 0.f, 0.f, 0.f}; \
    for (int k0 = 0; k0 < K; k0 += 32) { \
        const short* ga = A  + (size_t)(row0 + srow) * K + k0 + scol; \
        const short* gb = BT + (size_t)(col0 + srow) * K + k0 + scol; \
        __syncthreads(); \
        gl2lds16(ga,                  lAs0); \
        gl2lds16(ga + (size_t)64 * K, lAs1); \
        gl2lds16(gb,                  lBs0); \
        gl2lds16(gb + (size_t)64 * K, lBs1); \
        __syncthreads(); \
        bf16x8 af[4], bfv[4]; \
        _Pragma("unroll") \
        for (int mt = 0; mt < 4; ++mt) \
            af[mt] = *(const bf16x8*)&As[wr + mt * 16 + l16][quad * 8]; \
        _Pragma("unroll") \
        for (int nt = 0; nt < 4; ++nt) \
            bfv[nt] = *(const bf16x8*)&Bs[wc + nt * 16 + l16][quad * 8]; \
        _Pragma("unroll") \
        for (int mt = 0; mt < 4; ++mt) \
            _Pragma("unroll") \
            for (int nt = 0; nt < 4; ++nt) \
                acc[mt][nt] = __builtin_amdgcn_mfma_f32_16x16x32_bf16( \
                    af[mt], bfv[nt], acc[mt][nt], 0, 0, 0); \
    }

template <typename OT>
__global__ __launch_bounds__(256)
void gemm_mfma(const short* __restrict__ A, const short* __restrict__ BT,
               OT* __restrict__ C, int M, int N, int K)
{
    GEMM_PROLOG_128
    #pragma unroll
    for (int mt = 0; mt < 4; ++mt)
        #pragma unroll
        for (int nt = 0; nt < 4; ++nt) {
            const int col = col0 + wc + nt * 16 + l16;
            #pragma unroll
            for (int r = 0; r < 4; ++r) {
                const int row = row0 + wr + mt * 16 + quad * 4 + r;
                stf(C + (size_t)row * N + col, acc[mt][nt][r]);
            }
        }
}

// ---------------------------------------------------------------------------
// GEMM1 + fused Q-RMSNorm epilogue.
// ---------------------------------------------------------------------------
__global__ __launch_bounds__(256)
void gemm_qrms(const short* __restrict__ A, const short* __restrict__ BT,
               bf16* __restrict__ qn, const float* __restrict__ qg,
               int M, int N, int K)
{
    GEMM_PROLOG_128
    const int h = (col0 + wc) >> 6;
    const float g0 = qg[l16], g1 = qg[16 + l16];
    #pragma unroll
    for (int mt = 0; mt < 4; ++mt) {
        float ss[4];
        #pragma unroll
        for (int r = 0; r < 4; ++r)
            ss[r] = acc[mt][0][r] * acc[mt][0][r] + acc[mt][1][r] * acc[mt][1][r]
                  + acc[mt][2][r] * acc[mt][2][r] + acc[mt][3][r] * acc[mt][3][r];
        #pragma unroll
        for (int off = 1; off < 16; off <<= 1)
            #pragma unroll
            for (int r = 0; r < 4; ++r) ss[r] += __shfl_xor(ss[r], off, 64);
        #pragma unroll
        for (int r = 0; r < 4; ++r) {
            const float inv = 0.125f / sqrtf(ss[r] * (1.0f / HD_) + EPS_);
            const int row = row0 + wr + mt * 16 + quad * 4 + r;
            const int b = row >> 11, t = row & 2047;
            bf16* op = qn + (((size_t)(b * HH + h)) * TT + t) * RP;
            op[l16]      = __float2bfloat16(g0 * acc[mt][0][r] * inv);
            op[16 + l16] = __float2bfloat16(g1 * acc[mt][1][r] * inv);
        }
    }
}

// ---------------------------------------------------------------------------
// GEMM4 + fused K-RMSNorm / V-split epilogue.
// ---------------------------------------------------------------------------
__global__ __launch_bounds__(256)
void gemm_kv(const short* __restrict__ A, const short* __restrict__ BT,
             bf16* __restrict__ kn, bf16* __restrict__ vb,
             const float* __restrict__ kg, int M, int N, int K)
{
    GEMM_PROLOG_128
    const int colbase = col0 + wc;
    if (colbase < 512) {                        // K-RMS path
        const int h0 = colbase >> 5;            // groups h0, h0+1
        const float g0 = kg[l16], g1 = kg[16 + l16];
        #pragma unroll
        for (int mt = 0; mt < 4; ++mt) {
            float s0[4], s1[4];
            #pragma unroll
            for (int r = 0; r < 4; ++r) {
                s0[r] = acc[mt][0][r] * acc[mt][0][r] + acc[mt][1][r] * acc[mt][1][r];
                s1[r] = acc[mt][2][r] * acc[mt][2][r] + acc[mt][3][r] * acc[mt][3][r];
            }
            #pragma unroll
            for (int off = 1; off < 16; off <<= 1)
                #pragma unroll
                for (int r = 0; r < 4; ++r) {
                    s0[r] += __shfl_xor(s0[r], off, 64);
                    s1[r] += __shfl_xor(s1[r], off, 64);
                }
            #pragma unroll
            for (int r = 0; r < 4; ++r) {
                const float i0 = 1.0f / sqrtf(s0[r] * (1.0f / RP) + EPS_);
                const float i1 = 1.0f / sqrtf(s1[r] * (1.0f / RP) + EPS_);
                const int row = row0 + wr + mt * 16 + quad * 4 + r;
                const int b = row >> 11, t = row & 2047;
                bf16* op0 = kn + (((size_t)(b * HH + h0)) * TT + t) * RP;
                bf16* op1 = kn + (((size_t)(b * HH + h0 + 1)) * TT + t) * RP;
                op0[l16]      = __float2bfloat16(g0 * acc[mt][0][r] * i0);
                op0[16 + l16] = __float2bfloat16(g1 * acc[mt][1][r] * i0);
                op1[l16]      = __float2bfloat16(g0 * acc[mt][2][r] * i1);
                op1[16 + l16] = __float2bfloat16(g1 * acc[mt][3][r] * i1);
            }
        }
    } else {                                     // V path
        const int h0 = (colbase - 512) >> 5;
        #pragma unroll
        for (int mt = 0; mt < 4; ++mt)
            #pragma unroll
            for (int r = 0; r < 4; ++r) {
                const int row = row0 + wr + mt * 16 + quad * 4 + r;
                const int b = row >> 11, t = row & 2047;
                bf16* op0 = vb + (((size_t)(b * HH + h0)) * TT + t) * RP;
                bf16* op1 = vb + (((size_t)(b * HH + h0 + 1)) * TT + t) * RP;
                op0[l16]      = __float2bfloat16(acc[mt][0][r]);
                op0[16 + l16] = __float2bfloat16(acc[mt][1][r]);
                op1[l16]      = __float2bfloat16(acc[mt][2][r]);
                op1[16 + l16] = __float2bfloat16(acc[mt][3][r]);
            }
    }
}

// ---------------------------------------------------------------------------
// 64x128-tile GEMM (gemm3: 8192x128, K=1024 -> 128 blocks).
// ---------------------------------------------------------------------------
__global__ __launch_bounds__(256)
void gemm_k64(const short* __restrict__ A, const short* __restrict__ BT,
              bf16* __restrict__ C, int M, int N, int K)
{
    __shared__ __align__(16) short As[64][32];
    __shared__ __align__(16) short Bs[128][32];
    const int tid  = threadIdx.x;
    const int wave = tid >> 6, lane = tid & 63;
    const int quad = lane >> 4, l16 = lane & 15;
    const int wr = (wave >> 1) * 32, wc = (wave & 1) * 64;
    const int row0 = blockIdx.y * 64, col0 = blockIdx.x * 128;
    const int srow = tid >> 2, scol = (tid & 3) * 8;

    char* lAs  = (char*)As + wave * 1024;
    char* lBs0 = (char*)Bs + wave * 1024;
    char* lBs1 = (char*)Bs + 4096 + wave * 1024;

    f32x4 acc[2][4];
    #pragma unroll
    for (int mt = 0; mt < 2; ++mt)
        #pragma unroll
        for (int nt = 0; nt < 4; ++nt)
            acc[mt][nt] = (f32x4){0.f, 0.f, 0.f, 0.f};

    for (int k0 = 0; k0 < K; k0 += 32) {
        const short* ga = A  + (size_t)(row0 + srow) * K + k0 + scol;
        const short* gb = BT + (size_t)(col0 + srow) * K + k0 + scol;
        __syncthreads();
        gl2lds16(ga,                  lAs);
        gl2lds16(gb,                  lBs0);
        gl2lds16(gb + (size_t)64 * K, lBs1);
        __syncthreads();

        bf16x8 af[2], bfv[4];
        #pragma unroll
        for (int mt = 0; mt < 2; ++mt)
            af[mt] = *(const bf16x8*)&As[wr + mt * 16 + l16][quad * 8];
        #pragma unroll
        for (int nt = 0; nt < 4; ++nt)
            bfv[nt] = *(const bf16x8*)&Bs[wc + nt * 16 + l16][quad * 8];
        #pragma unroll
        for (int mt = 0; mt < 2; ++mt)
            #pragma unroll
            for (int nt = 0; nt < 4; ++nt)
                acc[mt][nt] = __builtin_amdgcn_mfma_f32_16x16x32_bf16(
                    af[mt], bfv[nt], acc[mt][nt], 0, 0, 0);
    }

    #pragma unroll
    for (int mt = 0; mt < 2; ++mt)
        #pragma unroll
        for (int nt = 0; nt < 4; ++nt) {
            const int col = col0 + wc + nt * 16 + l16;
            #pragma unroll
            for (int r = 0; r < 4; ++r) {
                const int row = row0 + wr + mt * 16 + quad * 4 + r;
                C[(size_t)row * N + col] = __float2bfloat16(acc[mt][nt][r]);
            }
        }
}

// ---------------------------------------------------------------------------
// V transpose: vb (bh, t, 32) -> vT (bh, 32, 2048).
// ---------------------------------------------------------------------------
__global__ __launch_bounds__(256)
void vtrans_kernel(const bf16* __restrict__ vb, bf16* __restrict__ vT)
{
    __shared__ __align__(16) short tile[32][72];
    const int bh = blockIdx.y;
    const int t0 = blockIdx.x * 64;
    const int tid = threadIdx.x;
    const int tl = tid >> 2, c0 = (tid & 3) * 8;
    bf16x8 v = *(const bf16x8*)(vb + ((size_t)bh * TT + t0 + tl) * RP + c0);
    #pragma unroll
    for (int j = 0; j < 8; ++j) tile[c0 + j][tl] = v[j];
    __syncthreads();
    const int c = tid >> 3, tt = (tid & 7) * 8;
    bf16x8 o = *(const bf16x8*)&tile[c][tt];
    *(bf16x8*)(vT + ((size_t)bh * RP + c) * TT + t0 + tt) = o;
}

// ---------------------------------------------------------------------------
// Flash MFMA attention v7: cooperative LDS staging + XOR swizzle + LDS
// DOUBLE-BUFFER with counted-wait pipeline (T3/T4 minimal 2-phase).
//  R10: per-step = barrier -> DMA -> barrier(drain) -> compute, exposing
//  full DMA latency (~40% of 46.6 us). Now: per step one inline-asm
//  "s_waitcnt vmcnt(0); s_barrier" at the TOP (waits the DMA issued one
//  compute-phase ago -> latency hidden), then issue next step's DMA into
//  the alternate buffer, then compute current buffer.
//  Hazards: barrier closes prev compute before buf[cur^1] overwrite (WAR);
//  each wave waits its own vmcnt before barrier, so after barrier ALL
//  waves' DMAs have landed (RAW). Tail prefetch reads <=4KB past the bh
//  slab into dead-but-mapped workspace, never consumed.
// ---------------------------------------------------------------------------
struct __attribute__((aligned(8))) bf4 { bf16 v[4]; };

__global__ __launch_bounds__(512, 4)
void attn_mfma(const bf16* __restrict__ qn, const bf16* __restrict__ kn,
               const bf16* __restrict__ vT, bf16* __restrict__ att)
{
    __shared__ __align__(16) short KsF[2][64 * 32];   // 8 KB, swizzled slots
    __shared__ __align__(16) short VsF[2][32 * 64];   // 8 KB, swizzled slots
    __shared__ __align__(16) bf16 P_lds[8][16][72];   // 18 KB
    const int tid  = threadIdx.x;
    const int w8   = tid >> 6, lane = tid & 63;
    const int quad = lane >> 4, l16 = lane & 15;
    // XCD-aware bijective remap: f -> (bx 0..7, bh 0..63), bh%8 == xcd
    const int f  = (int)(blockIdx.y * 8 + blockIdx.x);     // 0..511
    const int xr = f & 7, j = f >> 3;                       // j: 0..63
    const int bx = j & 7;
    const int bh = xr + 8 * (j >> 3);
    const int b = bh >> 4, h = bh & 15;

    const bf16* knb = kn + (size_t)bh * TT * RP;
    const bf16* vtb = vT + (size_t)bh * RP * TT;

    // staging map (LDS dest linear within buffer; source pre-swizzled):
    // K chunk c (=tid, waves 0-3): row=c>>2, gslot=(c&3)^((c>>3)&3)
    // V chunk c (=tid-256, waves 4-7): row=c>>3, gslot=(c&7)^((c>>3)&7)
    const bool isK = (w8 < 4);
    const int  cK = tid;
    const int  cV = tid - 256;
    const bf16* sBase = isK
        ? knb + (size_t)(cK >> 2) * RP + ((cK & 3) ^ ((cK >> 3) & 3)) * 8
        : vtb + (size_t)(cV >> 3) * TT + ((cV & 7) ^ ((cV >> 3) & 7)) * 8;
    const long long sStep = (long long)(isK ? RP : 1) * 64;  // per 64-row step
    const int ldsOff = isK ? w8 * 1024 : (w8 - 4) * 1024;

    // swizzled read offsets (in shorts)
    const int kslot = ((l16 >> 1) & 3);     // K frag: (quad^kslot)*8
    const int vswz  = (l16 & 7);            // V frag: ((ks*4+quad)^vswz)*8

    #pragma unroll 1
    for (int pi = 0; pi < 2; ++pi) {
        const int qt = pi ? (15 - bx) : bx;          // 128-row q-tile, 0..15
        const int NT = 2 * qt + 2;                   // 64-row KV steps
        const int qbase = qt * 128 + w8 * 16;

        if (pi) {
            // close pi=0 compute & drain stray tail prefetch before reusing buf0
            asm volatile("s_waitcnt vmcnt(0)\n\ts_barrier" ::: "memory");
        }

        bf16x8 qf = *(const bf16x8*)(qn + ((size_t)bh * TT + qbase + l16) * RP + quad * 8);

        float lsum = 0.f;
        f32x4 oacc0 = (f32x4){0.f, 0.f, 0.f, 0.f};
        f32x4 oacc1 = (f32x4){0.f, 0.f, 0.f, 0.f};

        // prologue: stage step 0 into buffer 0
        gl2lds16(sBase, (isK ? (char*)KsF[0] : (char*)VsF[0]) + ldsOff);
        int cur = 0;

        for (int st = 0; st < NT; ++st) {
            // wait my buf[cur] DMA (issued a full compute phase ago), then
            // barrier: all waves' DMAs landed AND prev compute closed.
            asm volatile("s_waitcnt vmcnt(0)\n\ts_barrier" ::: "memory");

            // issue next step's DMA into the alternate buffer (safe: WAR
            // closed by the barrier). Tail (st=NT-1) reads dead workspace.
            const int nxt = cur ^ 1;
            gl2lds16(sBase + (long long)(st + 1) * sStep,
                     (isK ? (char*)KsF[nxt] : (char*)VsF[nxt]) + ldsOff);

            const int s0 = st * 64;
            const short* KsC = KsF[cur];
            const short* VsC = VsF[cur];

            // ---- swapped QK^T from swizzled LDS: D[s_local][q=l16] ----
            f32x4 sc[4];
            #pragma unroll
            for (int sub = 0; sub < 4; ++sub) {
                bf16x8 kf = *(const bf16x8*)&KsC[(sub * 16 + l16) * 32
                                                 + ((quad ^ kslot) * 8)];
                sc[sub] = __builtin_amdgcn_mfma_f32_16x16x32_bf16(
                    kf, qf, (f32x4){0.f, 0.f, 0.f, 0.f}, 0, 0, 0);
            }

            // ---- causal mask (also zeroes fully-masked steps) ----
            if (s0 + 63 > qbase) {
                const int qg_ = qbase + l16;
                #pragma unroll
                for (int sub = 0; sub < 4; ++sub)
                    #pragma unroll
                    for (int r = 0; r < 4; ++r)
                        if (s0 + sub * 16 + quad * 4 + r > qg_) sc[sub][r] = -1e30f;
            }

            // ---- p = exp(sc), pack -> P_lds; per-lane partial sum ----
            #pragma unroll
            for (int sub = 0; sub < 4; ++sub) {
                const float p0 = __expf(sc[sub][0]);
                const float p1 = __expf(sc[sub][1]);
                const float p2 = __expf(sc[sub][2]);
                const float p3 = __expf(sc[sub][3]);
                bf4 pk;
                pk.v[0] = __float2bfloat16(p0);
                pk.v[1] = __float2bfloat16(p1);
                pk.v[2] = __float2bfloat16(p2);
                pk.v[3] = __float2bfloat16(p3);
                *(bf4*)&P_lds[w8][l16][sub * 16 + quad * 4] = pk;
                lsum += (p0 + p1) + (p2 + p3);
            }

            // ---- PV from swizzled LDS: D[q_local][c] ----
            #pragma unroll
            for (int ks = 0; ks < 2; ++ks) {
                bf16x8 pf  = *(const bf16x8*)&P_lds[w8][l16][ks * 32 + quad * 8];
                bf16x8 vf0 = *(const bf16x8*)&VsC[l16 * 64
                                + (((ks * 4 + quad) ^ vswz) * 8)];
                bf16x8 vf1 = *(const bf16x8*)&VsC[(16 + l16) * 64
                                + (((ks * 4 + quad) ^ vswz) * 8)];
                oacc0 = __builtin_amdgcn_mfma_f32_16x16x32_bf16(pf, vf0, oacc0, 0, 0, 0);
                oacc1 = __builtin_amdgcn_mfma_f32_16x16x32_bf16(pf, vf1, oacc1, 0, 0, 0);
            }

            cur = nxt;
        }

        // ---- epilogue (per wave) ----
        lsum += __shfl_xor(lsum, 16, 64);
        lsum += __shfl_xor(lsum, 32, 64);
        #pragma unroll
        for (int r = 0; r < 4; ++r) {
            const float ls = __shfl(lsum, quad * 20 + r, 64);
            const float inv = 1.0f / ls;
            const int t = qbase + quad * 4 + r;
            bf16* op = att + ((size_t)(b * TT + t)) * 512 + h * 32;
            op[l16]      = __float2bfloat16(oacc0[r] * inv);
            op[16 + l16] = __float2bfloat16(oacc1[r] * inv);
        }
    }
}

// ---------------------------------------------------------------------------
// Workspace (BYTE offsets from base = d_ws + 64):
//   xb    bf16 [0, 16777216)            (dead after gemm_k64)
//   wqT   bf16 [16777216, 18874368)     (dead after gemm_qrms; attn tail
//                                        prefetch may read here -> harmless)
//   wkvT  bf16 [18874368, 19136512)     (dead after gemm_k64)
//   kvb   bf16 [19136512, 21233664)     (dead after gemm_kv)
//   att_b bf16 [0, 8388608)             (alias over dead xb)
//   vTb   bf16 [8388608, 16777216)      (alias over dead xb)
//   qn    bf16 [35913728, 44302336)
//   kn    bf16 [44302336, 52690944)     (attn tail prefetch -> vb, harmless)
//   vb    bf16 [52690944, 61079552)     (dead after vtrans)
//   wkwvT bf16 [61079552, 61341696)
//   woT   bf16 [61341696, 62390272)
// ---------------------------------------------------------------------------
extern "C" void kernel_launch(void* const* d_in, const int* in_sizes, int n_in,
                              void* d_out, int out_size, void* d_ws, size_t ws_size,
                              hipStream_t stream)
{
    float* out = (float*)d_out;
    const long long NOUT = (long long)BB * TT * DD;
    const int outgrid = (int)((NOUT + 255) / 256);

    static const long long expect[8] =
        {8388608, 1048576, 131072, 65536, 65536, 1048576, 64, 32};
    if (n_in != 8) {
        sentinel_kernel<<<outgrid, 256, 0, stream>>>(out, 20000.0f + 100.0f * n_in, NOUT);
        return;
    }
    for (int i = 0; i < 8; ++i) {
        if ((long long)in_sizes[i] != expect[i]) {
            sentinel_kernel<<<outgrid, 256, 0, stream>>>(out, 10000.0f + 1000.0f * i, NOUT);
            return;
        }
    }
    if (ws_size < 62914624ULL) {
        sentinel_kernel<<<outgrid, 256, 0, stream>>>(
            out, 30000.0f + (float)(ws_size >> 20), NOUT);
        return;
    }
    if (out_size != 8388608) {
        sentinel_kernel<<<outgrid, 256, 0, stream>>>(
            out, 512.0f * (1.0f + (float)(out_size >> 20)), NOUT);
        return;
    }

    const float* x   = (const float*)d_in[0];
    const float* Wq  = (const float*)d_in[1];
    const float* Wkv = (const float*)d_in[2];
    const float* Wk  = (const float*)d_in[3];
    const float* Wv  = (const float*)d_in[4];
    const float* Wo  = (const float*)d_in[5];
    const float* qg  = (const float*)d_in[6];
    const float* kg  = (const float*)d_in[7];

    char* base = (char*)d_ws + 64;
    bf16*  xb    = (bf16*)(base + 0);
    bf16*  wqT   = (bf16*)(base + 16777216);
    bf16*  wkvT  = (bf16*)(base + 18874368);
    bf16*  kvb   = (bf16*)(base + 19136512);
    bf16*  att_b = (bf16*)(base + 0);
    bf16*  vTb   = (bf16*)(base + 8388608);
    bf16*  qn    = (bf16*)(base + 35913728);
    bf16*  kn    = (bf16*)(base + 44302336);
    bf16*  vb    = (bf16*)(base + 52690944);
    bf16*  wkwvT = (bf16*)(base + 61079552);
    bf16*  woT   = (bf16*)(base + 61341696);

    const int BT = BB * TT;                    // 8192

    // 0. converts
    conv_x_kernel<<<outgrid / 4, 256, 0, stream>>>(x, xb, NOUT / 4);
    conv_trans_kernel<<<dim3(16, 16), 256, 0, stream>>>(Wq, wqT, 1024, 1024);
    conv_trans_kernel<<<dim3(2, 16), 256, 0, stream>>>(Wkv, wkvT, 1024, 128);
    conv_wkwv_kernel<<<512, 256, 0, stream>>>(Wk, Wv, wkwvT);
    conv_woT_kernel<<<dim3(16, 8), 256, 0, stream>>>(Wo, woT);

    // 1. qn = rmsnorm(xb @ Wq)[:, :32] * 0.125 (fused GEMM+RMS epilogue)
    gemm_qrms<<<dim3(8, 64), 256, 0, stream>>>(
        (const short*)xb, (const short*)wqT, qn, qg, BT, DD, DD);
    // 2. kvb = xb @ Wkv (64-row tiles -> 128 blocks), 8192x128, K=1024
    gemm_k64<<<dim3(1, 128), 256, 0, stream>>>(
        (const short*)xb, (const short*)wkvT, kvb, BT, LAT_, DD);
    // 3. kn/vb = fused(kvb @ [Wk|Wv]) (GEMM + K-RMS/V-split epilogue)
    gemm_kv<<<dim3(8, 64), 256, 0, stream>>>(
        (const short*)kvb, (const short*)wkwvT, kn, vb, kg, BT, 2 * 512, LAT_);
    // 4. vT = transpose(vb)
    vtrans_kernel<<<dim3(32, 64), 256, 0, stream>>>(vb, vTb);
    // 5. flash MFMA attention (dbuf LDS staging, counted-wait pipeline)
    attn_mfma<<<dim3(8, 64), 512, 0, stream>>>(qn, kn, vTb, att_b);
    // 6. out = att_b @ Wo_remap (MFMA), 8192x1024, K=512
    gemm_mfma<float><<<dim3(8, 64), 256, 0, stream>>>(
        (const short*)att_b, (const short*)woT, out, BT, DD, 512);
}